// Round 4
// baseline (1618.412 us; speedup 1.0000x reference)
//
#include <hip/hip_runtime.h>
#include <hip/hip_bf16.h>

typedef float f32x4 __attribute__((ext_vector_type(4)));
typedef short s16x8 __attribute__((ext_vector_type(8)));
typedef unsigned short u16;

#define BT 16        // batch rows per group
#define NWG 256      // 64 groups x 4 WGs (h-split)
#define H 128
#define VW 256
#define NI 64
#define NSTEPS 64

// ws layout (u16 units): bf16-packed weight tiles.
// Fragment layout: [(kk*NT + nt)*64 + lane]*8 + j -> B[k = kk*32 + (lane>>4)*8 + j][col = nt*16 + (lane&15)]
#define OFF_W1L 0          // GEMM1: KK=4,  NT=16 -> 32768 u16
#define OFF_W2L 32768      // GEMM2: KK=8,  NT=16 -> 65536 u16
#define OFF_WML 98304      // GEMM3: KK=169, NT=8 -> 692224 u16 (kk 168 = bm bias block)
#define WS_TOTAL 790528
// after weights (byte offsets from ws base, in bytes):
//   epochs: 256 writers x 64B = 16 KB  (u32[(g*4+t)*16])
//   ybuf  : u32[2][64][4][256] = 512 KB

#define MFMA(a, b, c) __builtin_amdgcn_mfma_f32_16x16x32_bf16(a, b, c, 0, 0, 0)

__device__ __forceinline__ u16 bf16u(float f) {
  union { float f; unsigned u; } x; x.f = f;
  return (u16)((x.u + 0x7fffu + ((x.u >> 16) & 1u)) >> 16);  // RNE
}
__device__ __forceinline__ float b2f(u16 u) {
  union { unsigned u; float f; } x; x.u = ((unsigned)u) << 16;
  return x.f;
}
__device__ __forceinline__ float tanh_fast(float x) {
  float e = __expf(2.f * x);
  return 1.f - 2.f * __builtin_amdgcn_rcpf(e + 1.f);
}

__global__ void prep_weights(const float* __restrict__ Wvf1,
                             const float* __restrict__ Wvf2,
                             const float* __restrict__ Wm,
                             const float* __restrict__ bmv,
                             u16* __restrict__ ws) {
  int idx = blockIdx.x * blockDim.x + threadIdx.x;
  if (idx < 4096) ((unsigned*)(ws + WS_TOTAL))[idx] = 0u;  // zero epochs each call
  if (idx >= WS_TOTAL) return;
  float val;
  if (idx < OFF_W2L) {
    int e = idx;
    int j = e & 7, ln = (e >> 3) & 63, nt = (e >> 9) & 15, kk = e >> 13;
    int cc = ln & 15, kgg = ln >> 4;
    val = Wvf1[(nt * 16 + cc) * H + kk * 32 + kgg * 8 + j];
  } else if (idx < OFF_WML) {
    int e = idx - OFF_W2L;
    int j = e & 7, ln = (e >> 3) & 63, nt = (e >> 9) & 15, kk = e >> 13;
    int cc = ln & 15, kgg = ln >> 4;
    val = Wvf2[(nt * 16 + cc) * VW + kk * 32 + kgg * 8 + j];
  } else {
    int e = idx - OFF_WML;
    int j = e & 7, ln = (e >> 3) & 63, nt = (e >> 9) & 7, kkg = e >> 12;
    int cc = ln & 15, kgg = ln >> 4;
    int h = nt * 16 + cc;
    if (kkg < 168) {
      int l = kkg >> 3;
      int w = (kkg & 7) * 32 + kgg * 8 + j;
      val = Wm[(size_t)(h * 21 + l) * VW + w];
    } else {
      int m = kgg * 8 + j;
      val = (m < 21) ? bmv[h * 21 + m] : 0.f;
    }
  }
  ws[idx] = bf16u(val);
}

__global__ __launch_bounds__(512, 2) void rde_main(
    const float* __restrict__ logsig, const float* __restrict__ x0,
    const float* __restrict__ W1, const float* __restrict__ b1,
    const float* __restrict__ bvf1, const float* __restrict__ bvf2,
    const float* __restrict__ W2, const float* __restrict__ b2,
    const u16* __restrict__ ws, unsigned* __restrict__ epk,
    unsigned* __restrict__ ybuf, float* __restrict__ out) {
  __shared__ __align__(16) u16   W1Ls[OFF_W2L];     // GEMM1 weights (64 KB)
  __shared__ __align__(16) u16   YB [BT][H + 8];    // full bf16 y (GEMM1 A)
  __shared__ __align__(16) u16   V1R[BT][VW + 8];   // bf16 relu(v1)
  __shared__ __align__(16) u16   V2B[BT][VW + 8];   // bf16 tanh(v2)
  __shared__ __align__(16) float LSF[2][21][BT];    // f32 ls, ping-pong by interval parity
  __shared__ __align__(16) u16   LSB[2][BT][40];    // bf16 ls padded to 32
  __shared__ __align__(16) float part[4][BT][32];   // GEMM3 l-subset partials
  __shared__ float LG[BT][10];

  const int tid = threadIdx.x;
  const int lane = tid & 63;
  const int wv = tid >> 6;     // 0..7
  const int c = lane & 15;
  const int kg = lane >> 4;

  // group decomposition: members of a group land on the same XCD (perf heuristic only)
  const int bid = blockIdx.x;
  const int g = (bid & 7) * 8 + ((bid >> 3) >> 2);  // 0..63
  const int t = (bid >> 3) & 3;                     // h-quarter role 0..3
  const int b0 = g * BT;
  unsigned* myep = epk + (g * 4 + t) * 16;          // 64B-strided epochs

  const s16x8* __restrict__ sws = (const s16x8*)ws;
  const f32x4 zf = {0.f, 0.f, 0.f, 0.f};

  // ---- persistent register weights
  s16x8 w2r[2][8];
#pragma unroll
  for (int t2 = 0; t2 < 2; ++t2)
#pragma unroll
    for (int kk = 0; kk < 8; ++kk)
      w2r[t2][kk] = sws[OFF_W2L / 8 + (kk * 16 + wv * 2 + t2) * 64 + lane];
  const int nt = wv & 1;        // n-tile within quarter
  const int jq = wv >> 1;       // l-subset 0..3 (contiguous ranges)
  const int ntg = t * 2 + nt;   // global n-tile 0..7
  const int l0g = (jq == 0) ? 0 : (5 * jq + 1);  // jq0:0-5(6), jq1:6-10, jq2:11-15, jq3:16-20
  s16x8 wbias = sws[OFF_WML / 8 + (168 * 8 + ntg) * 64 + lane];
  const float bv1a = bvf1[wv * 32 + c], bv1b = bvf1[wv * 32 + 16 + c];
  const float bv2a = bvf2[wv * 32 + c], bv2b = bvf2[wv * 32 + 16 + c];

  for (int e = tid; e < OFF_W2L / 8; e += 512) ((s16x8*)W1Ls)[e] = sws[e];
  for (int e = tid; e < 2 * BT * 40; e += 512) ((u16*)LSB)[e] = 0;

  // ---- y0 = x0 @ W1^T + b1 : full bf16 YB (redundant) + own f32 state element
  for (int e = tid; e < BT * H; e += 512) {
    int r = e >> 7, h = e & 127;
    float a = b1[h];
#pragma unroll
    for (int d = 0; d < 6; ++d) a += x0[(b0 + r) * 6 + d] * W1[h * 6 + d];
    YB[r][h] = bf16u(a);
  }
  float y_st, yp_st = 0.f;
  {
    int r = tid >> 5, h = t * 32 + (tid & 31);
    float a = b1[h];
#pragma unroll
    for (int d = 0; d < 6; ++d) a += x0[(b0 + r) * 6 + d] * W1[h * 6 + d];
    y_st = a;
  }
  __syncthreads();

  const s16x8* wb3 = sws + OFF_WML / 8 + ntg * 64 + lane;
  int phase = 0;

#define G3_LOADG(P, L)                                                         \
  do {                                                                         \
    P##0 = wb3[((L) * 8 + 0) * 512]; P##1 = wb3[((L) * 8 + 1) * 512];          \
    P##2 = wb3[((L) * 8 + 2) * 512]; P##3 = wb3[((L) * 8 + 3) * 512];          \
    P##4 = wb3[((L) * 8 + 4) * 512]; P##5 = wb3[((L) * 8 + 5) * 512];          \
    P##6 = wb3[((L) * 8 + 6) * 512]; P##7 = wb3[((L) * 8 + 7) * 512];          \
  } while (0)

#define G3_STEPG(P, L)                                                         \
  do {                                                                         \
    f32x4 P0 = MFMA(ag0, P##0, zf); f32x4 P1 = MFMA(ag4, P##4, zf);            \
    P0 = MFMA(ag1, P##1, P0);       P1 = MFMA(ag5, P##5, P1);                  \
    P0 = MFMA(ag2, P##2, P0);       P1 = MFMA(ag6, P##6, P1);                  \
    P0 = MFMA(ag3, P##3, P0);       P1 = MFMA(ag7, P##7, P1);                  \
    f32x4 lsq = *(const f32x4*)&LSF[lsb][(L)][kg * 4];                         \
    _Pragma("unroll")                                                          \
    for (int qq = 0; qq < 4; ++qq) acc[qq] += lsq[qq] * (P0[qq] + P1[qq]);     \
  } while (0)

  // 3-deep B-fragment ring, prefetched ahead of each eval (survives the exchange)
  s16x8 xa0, xa1, xa2, xa3, xa4, xa5, xa6, xa7;
  s16x8 xb0, xb1, xb2, xb3, xb4, xb5, xb6, xb7;
  s16x8 xc0, xc1, xc2, xc3, xc4, xc5, xc6, xc7;
  G3_LOADG(xa, l0g); G3_LOADG(xb, l0g + 1); G3_LOADG(xc, l0g + 2);

#pragma unroll 1
  for (int step = 0; step < NSTEPS; ++step) {
#pragma unroll 1
    for (int sub = 0; sub < 2; ++sub) {
      const int jint = sub ? step : (step > 0 ? step - 1 : 0);
      const int lsb = jint & 1;

      if (sub == 0 && tid < BT * 21) {
        int r = tid / 21, l = tid % 21;
        float v = logsig[((size_t)(b0 + r) * NI + step) * 22 + 1 + l];
        LSF[step & 1][l][r] = v;
        LSB[step & 1][r][l] = bf16u(v);
      }

      // ---- GEMM1 (redundant, full width): v1 = relu(y @ W_vf1^T + b_vf1)
      {
        s16x8 ay0 = *(const s16x8*)&YB[c][0 * 32 + kg * 8];
        s16x8 ay1 = *(const s16x8*)&YB[c][1 * 32 + kg * 8];
        s16x8 ay2 = *(const s16x8*)&YB[c][2 * 32 + kg * 8];
        s16x8 ay3 = *(const s16x8*)&YB[c][3 * 32 + kg * 8];
        f32x4 p0 = zf, p1 = zf;
#pragma unroll
        for (int kk = 0; kk < 4; ++kk) {
          s16x8 bA = *(const s16x8*)&W1Ls[((kk * 16 + wv * 2 + 0) * 64 + lane) * 8];
          s16x8 bB = *(const s16x8*)&W1Ls[((kk * 16 + wv * 2 + 1) * 64 + lane) * 8];
          s16x8 a = (kk == 0) ? ay0 : (kk == 1) ? ay1 : (kk == 2) ? ay2 : ay3;
          p0 = MFMA(a, bA, p0);
          p1 = MFMA(a, bB, p1);
        }
        int col = wv * 32 + c;
#pragma unroll
        for (int q = 0; q < 4; ++q) V1R[kg * 4 + q][col] = bf16u(fmaxf(p0[q] + bv1a, 0.f));
#pragma unroll
        for (int q = 0; q < 4; ++q) V1R[kg * 4 + q][col + 16] = bf16u(fmaxf(p1[q] + bv1b, 0.f));
      }
      __syncthreads();

      // ---- GEMM2 (redundant, full width): v2 = tanh(v1 @ W_vf2^T + b_vf2)
      {
        s16x8 av0 = *(const s16x8*)&V1R[c][0 * 32 + kg * 8];
        s16x8 av1 = *(const s16x8*)&V1R[c][1 * 32 + kg * 8];
        s16x8 av2 = *(const s16x8*)&V1R[c][2 * 32 + kg * 8];
        s16x8 av3 = *(const s16x8*)&V1R[c][3 * 32 + kg * 8];
        s16x8 av4 = *(const s16x8*)&V1R[c][4 * 32 + kg * 8];
        s16x8 av5 = *(const s16x8*)&V1R[c][5 * 32 + kg * 8];
        s16x8 av6 = *(const s16x8*)&V1R[c][6 * 32 + kg * 8];
        s16x8 av7 = *(const s16x8*)&V1R[c][7 * 32 + kg * 8];
        f32x4 p0a = zf, p0b = zf, p1a = zf, p1b = zf;
        p0a = MFMA(av0, w2r[0][0], p0a); p1a = MFMA(av0, w2r[1][0], p1a);
        p0b = MFMA(av4, w2r[0][4], p0b); p1b = MFMA(av4, w2r[1][4], p1b);
        p0a = MFMA(av1, w2r[0][1], p0a); p1a = MFMA(av1, w2r[1][1], p1a);
        p0b = MFMA(av5, w2r[0][5], p0b); p1b = MFMA(av5, w2r[1][5], p1b);
        p0a = MFMA(av2, w2r[0][2], p0a); p1a = MFMA(av2, w2r[1][2], p1a);
        p0b = MFMA(av6, w2r[0][6], p0b); p1b = MFMA(av6, w2r[1][6], p1b);
        p0a = MFMA(av3, w2r[0][3], p0a); p1a = MFMA(av3, w2r[1][3], p1a);
        p0b = MFMA(av7, w2r[0][7], p0b); p1b = MFMA(av7, w2r[1][7], p1b);
        int col = wv * 32 + c;
#pragma unroll
        for (int q = 0; q < 4; ++q) V2B[kg * 4 + q][col] = bf16u(tanh_fast(p0a[q] + p0b[q] + bv2a));
#pragma unroll
        for (int q = 0; q < 4; ++q) V2B[kg * 4 + q][col + 16] = bf16u(tanh_fast(p1a[q] + p1b[q] + bv2b));
      }
      __syncthreads();

      // ---- GEMM3 (own h-quarter): wave (nt, jq) does contiguous l-range, ring-prefetched
      {
        s16x8 ag0 = *(const s16x8*)&V2B[c][0 * 32 + kg * 8];
        s16x8 ag1 = *(const s16x8*)&V2B[c][1 * 32 + kg * 8];
        s16x8 ag2 = *(const s16x8*)&V2B[c][2 * 32 + kg * 8];
        s16x8 ag3 = *(const s16x8*)&V2B[c][3 * 32 + kg * 8];
        s16x8 ag4 = *(const s16x8*)&V2B[c][4 * 32 + kg * 8];
        s16x8 ag5 = *(const s16x8*)&V2B[c][5 * 32 + kg * 8];
        s16x8 ag6 = *(const s16x8*)&V2B[c][6 * 32 + kg * 8];
        s16x8 ag7 = *(const s16x8*)&V2B[c][7 * 32 + kg * 8];
        f32x4 acc = zf;
        G3_STEPG(xa, l0g + 0); G3_LOADG(xa, l0g + 3);
        G3_STEPG(xb, l0g + 1); G3_LOADG(xb, l0g + 4);
        G3_STEPG(xc, l0g + 2);
        if (jq == 0) G3_LOADG(xc, l0g + 5);
        G3_STEPG(xa, l0g + 3);
        G3_STEPG(xb, l0g + 4);
        if (jq == 0) G3_STEPG(xc, l0g + 5);
        if (jq == 3) {  // bias block: A = ls (bf16, zero-padded), B = bm tile
          s16x8 als = *(const s16x8*)&LSB[lsb][c][kg * 8];
          f32x4 Pb = MFMA(als, wbias, zf);
#pragma unroll
          for (int q = 0; q < 4; ++q) acc[q] += Pb[q];
        }
        // tail prefetch for NEXT eval: streams through the exchange window
        G3_LOADG(xa, l0g); G3_LOADG(xb, l0g + 1); G3_LOADG(xc, l0g + 2);
#pragma unroll
        for (int q = 0; q < 4; ++q) part[jq][kg * 4 + q][nt * 16 + c] = acc[q];
      }
      __syncthreads();

      // ---- Heun epilogue (thread owns element (r, t*32+hh)) + y exchange
      {
        int r = tid >> 5, hh = tid & 31;
        float raw = part[0][r][hh] + part[1][r][hh] + part[2][r][hh] + part[3][r][hh];
        u16 yb16;
        if (sub == 0) {
          yp_st = y_st + 0.5f * raw;
          yb16 = bf16u(y_st + raw);
        } else {
          y_st = yp_st + 0.5f * raw;
          yb16 = bf16u(y_st);
        }
        unsigned vv = yb16;
        unsigned up = (unsigned)__shfl_down((int)vv, 1);
        if ((hh & 1) == 0) {
          unsigned packed = vv | (up << 16);
          unsigned off = (unsigned)((phase & 1) * 65536 + g * 1024 + t * 256 + (tid >> 1));
          __hip_atomic_store(&ybuf[off], packed, __ATOMIC_RELAXED, __HIP_MEMORY_SCOPE_AGENT);
        }
      }
      __syncthreads();  // barrier drains payload stores (vmcnt) before epoch release
      if (tid == 0)
        __hip_atomic_store(myep, (unsigned)(phase + 1), __ATOMIC_RELAXED, __HIP_MEMORY_SCOPE_AGENT);
      if (wv == 0) {  // single-wave poll: lanes 0..3 watch the 4 epochs
        unsigned tgt = (unsigned)(phase + 1);
        for (int sp = 0; sp < 50000; ++sp) {
          unsigned e = tgt;
          if (lane < 4)
            e = __hip_atomic_load(&epk[(g * 4 + lane) * 16], __ATOMIC_RELAXED, __HIP_MEMORY_SCOPE_AGENT);
          if (__all((int)(e >= tgt))) break;
        }
      }
      __syncthreads();
      asm volatile("" ::: "memory");
      {  // rebuild full YB from the 4 quarters
        const unsigned* srcb = ybuf + (phase & 1) * 65536 + g * 1024;
        for (int e2 = tid; e2 < 1024; e2 += 512) {
          unsigned pv = __hip_atomic_load(&srcb[e2], __ATOMIC_RELAXED, __HIP_MEMORY_SCOPE_AGENT);
          int tp = e2 >> 8, rem = e2 & 255;
          int rr = rem >> 4, cc2 = (rem & 15) << 1;
          YB[rr][tp * 32 + cc2]     = (u16)(pv & 0xffffu);
          YB[rr][tp * 32 + cc2 + 1] = (u16)(pv >> 16);
        }
      }
      __syncthreads();
      ++phase;
    }
  }

  // ---- logits + softmax from final bf16 y (t==0 only writes out)
  if (t == 0) {
    if (tid < 160) {
      int r = tid / 10, cc = tid % 10;
      float a = b2[cc];
#pragma unroll 4
      for (int h = 0; h < H; ++h) a += b2f(YB[r][h]) * W2[cc * H + h];
      LG[r][cc] = a;
    }
    __syncthreads();
    if (tid < 16) {
      float m = -1e30f;
#pragma unroll
      for (int cc = 0; cc < 10; ++cc) m = fmaxf(m, LG[tid][cc]);
      float ex[10]; float s = 0.f;
#pragma unroll
      for (int cc = 0; cc < 10; ++cc) { ex[cc] = expf(LG[tid][cc] - m); s += ex[cc]; }
      float inv = 1.f / s;
#pragma unroll
      for (int cc = 0; cc < 10; ++cc) out[(b0 + tid) * 10 + cc] = ex[cc] * inv;
    }
  }
}

extern "C" void kernel_launch(void* const* d_in, const int* in_sizes, int n_in,
                              void* d_out, int out_size, void* d_ws, size_t ws_size,
                              hipStream_t stream) {
  (void)in_sizes; (void)n_in; (void)out_size; (void)ws_size;
  const float* logsig = (const float*)d_in[1];
  const float* x0     = (const float*)d_in[2];
  const float* Wvf1   = (const float*)d_in[3];
  const float* bvf1   = (const float*)d_in[4];
  const float* Wvf2   = (const float*)d_in[5];
  const float* bvf2   = (const float*)d_in[6];
  const float* Wm     = (const float*)d_in[7];
  const float* bmv    = (const float*)d_in[8];
  const float* W1     = (const float*)d_in[9];
  const float* b1     = (const float*)d_in[10];
  const float* W2     = (const float*)d_in[11];
  const float* b2     = (const float*)d_in[12];
  u16* ws = (u16*)d_ws;
  unsigned* epk  = (unsigned*)((char*)d_ws + (size_t)WS_TOTAL * 2);
  unsigned* ybuf = (unsigned*)((char*)d_ws + (size_t)WS_TOTAL * 2 + 16384);

  prep_weights<<<(WS_TOTAL + 255) / 256, 256, 0, stream>>>(Wvf1, Wvf2, Wm, bmv, ws);
  rde_main<<<NWG, 512, 0, stream>>>(logsig, x0, W1, b1, bvf1, bvf2, W2, b2, ws,
                                    epk, ybuf, (float*)d_out);
}

// Round 5
// 1113.165 us; speedup vs baseline: 1.4539x; 1.4539x over previous
//
#include <hip/hip_runtime.h>
#include <hip/hip_bf16.h>

typedef float f32x4 __attribute__((ext_vector_type(4)));
typedef int   i32x4 __attribute__((ext_vector_type(4)));
typedef short s16x8 __attribute__((ext_vector_type(8)));
typedef unsigned short u16;

#define NG 32        // groups
#define BT 32        // batch rows per group
#define NWG 256      // 32 groups x 8 WGs (h-split by 16)
#define NTH 256      // threads per WG (4 waves)
#define H 128
#define VW 256
#define NI 64
#define NSTEPS 64

// ws BYTE layout:
#define OFF_FRAG16 0        // u16 frags: W1 (32768 u16) + W2 (65536 u16) = 196608 B
#define OFF_WMQ    196608   // i8 frags [slice8][l21][kk4][lane64][16] = 688128 B
#define OFF_BMF    884736   // f32 [slice8][l21][hh16] = 10752 B
#define OFF_SCF    895488   // f32[128] dequant scale (max_h/127^2)
#define OFF_SINV   896000   // f32[128] pack scale (127/max_h)
#define OFF_EPOCH  896512   // u32, 256 slots * 64B stride = 16384 B
#define OFF_YBUF   912896   // u32 [2][32][2048] = 524288 B

#define MFMA_BF16(a,b,c) __builtin_amdgcn_mfma_f32_16x16x32_bf16(a,b,c,0,0,0)
#define MFMA_I8(a,b,c)   __builtin_amdgcn_mfma_i32_16x16x64_i8(a,b,c,0,0,0)

__device__ __forceinline__ u16 bf16u(float f) {
  union { float f; unsigned u; } x; x.f = f;
  return (u16)((x.u + 0x7fffu + ((x.u >> 16) & 1u)) >> 16);  // RNE
}
__device__ __forceinline__ float b2f(u16 u) {
  union { unsigned u; float f; } x; x.u = ((unsigned)u) << 16;
  return x.f;
}

// -------- prep 1: per-h max of |Wm|, scales; zero epochs --------
__global__ void prep_scales(const float* __restrict__ Wm, char* __restrict__ ws) {
  __shared__ float red[4];
  const int tid = threadIdx.x;
  const int h = blockIdx.x;
  float m = 0.f;
  for (int i = tid; i < 21 * VW; i += NTH) m = fmaxf(m, fabsf(Wm[h * 21 * VW + i]));
  for (int off = 32; off > 0; off >>= 1) m = fmaxf(m, __shfl_down(m, off));
  if ((tid & 63) == 0) red[tid >> 6] = m;
  __syncthreads();
  if (tid == 0) {
    m = fmaxf(fmaxf(red[0], red[1]), fmaxf(red[2], red[3]));
    m = fmaxf(m, 1e-20f);
    ((float*)(ws + OFF_SCF))[h]  = m / 16129.f;   // max/(127*127)
    ((float*)(ws + OFF_SINV))[h] = 127.f / m;
  }
  if (blockIdx.x == 0)
    for (int i = tid; i < 4096; i += NTH) ((unsigned*)(ws + OFF_EPOCH))[i] = 0u;
}

// -------- prep 2: pack W1/W2 bf16 frags, Wm i8 frags, bm slices --------
__global__ void prep_pack(const float* __restrict__ Wvf1, const float* __restrict__ Wvf2,
                          const float* __restrict__ Wm, const float* __restrict__ bmv,
                          char* __restrict__ ws) {
  int idx = blockIdx.x * blockDim.x + threadIdx.x;
  if (idx < 98304) {
    u16* w16 = (u16*)(ws + OFF_FRAG16);
    float val;
    if (idx < 32768) {
      int e = idx;
      int j = e & 7, ln = (e >> 3) & 63, nt = (e >> 9) & 15, kk = e >> 13;
      val = Wvf1[(nt * 16 + (ln & 15)) * H + kk * 32 + (ln >> 4) * 8 + j];
    } else {
      int e = idx - 32768;
      int j = e & 7, ln = (e >> 3) & 63, nt = (e >> 9) & 15, kk = e >> 13;
      val = Wvf2[(nt * 16 + (ln & 15)) * VW + kk * 32 + (ln >> 4) * 8 + j];
    }
    w16[idx] = bf16u(val);
  } else if (idx < 98304 + 688128) {
    int b = idx - 98304;
    int j = b & 15, lane = (b >> 4) & 63, kk = (b >> 10) & 3, rem = b >> 12;
    int l = rem % 21, nt = rem / 21;
    int h = nt * 16 + (lane & 15);
    int w = kk * 64 + (lane >> 4) * 16 + j;
    float sinv = ((const float*)(ws + OFF_SINV))[h];
    float val = Wm[(size_t)(h * 21 + l) * VW + w];
    int q = (int)lrintf(val * sinv);
    q = min(127, max(-127, q));
    ((signed char*)(ws + OFF_WMQ))[b] = (signed char)q;
  } else if (idx < 98304 + 688128 + 2688) {
    int b = idx - (98304 + 688128);
    int hh = b & 15, rem = b >> 4;
    int l = rem % 21, nt = rem / 21;
    ((float*)(ws + OFF_BMF))[b] = bmv[(nt * 16 + hh) * 21 + l];
  }
}

// -------- main persistent kernel --------
__global__ __launch_bounds__(NTH, 1) void rde_main(
    const float* __restrict__ logsig, const float* __restrict__ x0,
    const float* __restrict__ W1, const float* __restrict__ b1,
    const float* __restrict__ bvf1, const float* __restrict__ bvf2,
    const float* __restrict__ W2, const float* __restrict__ b2,
    char* __restrict__ ws, float* __restrict__ out) {
  __shared__ __align__(16) signed char WmL[86016];     // i8 Wm slice, frag-linear
  __shared__ __align__(16) u16   YB [BT][H + 8];       // bf16 y (full)
  __shared__ __align__(16) u16   V1R[BT][VW + 8];      // bf16 relu(v1)
  __shared__ __align__(16) signed char V2QH[8192];     // i8 v2 hi, frag-linear
  __shared__ __align__(16) signed char V2QL[8192];     // i8 v2 lo (residual*254)
  __shared__ __align__(16) float LSF[2][21][BT];       // f32 ls, parity ping-pong
  __shared__ __align__(16) float part[4][2][16][17];   // per-wave GEMM3 partials
  __shared__ __align__(16) float bmL[336];             // bm slice [l][hh]
  __shared__ float scL[16];
  __shared__ float LG[BT][10];

  const int tid = threadIdx.x;
  const int lane = tid & 63;
  const int wv = tid >> 6;     // 0..3
  const int c = lane & 15;
  const int kg = lane >> 4;
  const int bid = blockIdx.x;
  const int g = (bid & 7) * 4 + (bid >> 6);   // 0..31 (members share bid%8 -> same XCD heuristic)
  const int t = (bid >> 3) & 7;               // h-slice 0..7
  const int b0 = g * BT;
  unsigned* __restrict__ epk  = (unsigned*)(ws + OFF_EPOCH);
  unsigned* __restrict__ ybuf = (unsigned*)(ws + OFF_YBUF);
  unsigned* myep = epk + (g * 8 + t) * 16;
  const s16x8* __restrict__ fr16 = (const s16x8*)(ws + OFF_FRAG16);
  const f32x4 zf = {0.f, 0.f, 0.f, 0.f};
  const i32x4 zi = {0, 0, 0, 0};

  // persistent register weights (cap 512 regs at this occupancy -> no spill)
  s16x8 w1r[4][4], w2r[4][8];
#pragma unroll
  for (int n = 0; n < 4; ++n) {
#pragma unroll
    for (int kk = 0; kk < 4; ++kk) w1r[n][kk] = fr16[(kk * 16 + wv * 4 + n) * 64 + lane];
#pragma unroll
    for (int kk = 0; kk < 8; ++kk) w2r[n][kk] = fr16[4096 + (kk * 16 + wv * 4 + n) * 64 + lane];
  }
  float bv1[4], bv2[4];
#pragma unroll
  for (int n = 0; n < 4; ++n) {
    bv1[n] = bvf1[wv * 64 + n * 16 + c];
    bv2[n] = bvf2[wv * 64 + n * 16 + c];
  }

  // Wm slice -> LDS (once)
  {
    const i32x4* wsrc = (const i32x4*)(ws + OFF_WMQ + t * 86016);
    i32x4* wdst = (i32x4*)WmL;
    for (int e = tid; e < 5376; e += NTH) wdst[e] = wsrc[e];
  }
  if (tid < 16) scL[tid] = ((const float*)(ws + OFF_SCF))[t * 16 + tid];
  for (int e = tid; e < 336; e += NTH) bmL[e] = ((const float*)(ws + OFF_BMF))[t * 336 + e];

  // y0 = x0 @ W1^T + b1
  for (int e = tid; e < BT * H; e += NTH) {
    int r = e >> 7, h = e & 127;
    float a = b1[h];
#pragma unroll
    for (int d = 0; d < 6; ++d) a += x0[(b0 + r) * 6 + d] * W1[h * 6 + d];
    YB[r][h] = bf16u(a);
  }
  float y_st[2], yp_st[2];
  yp_st[0] = yp_st[1] = 0.f;
#pragma unroll
  for (int p = 0; p < 2; ++p) {
    int ii = p * NTH + tid;
    int r = ii >> 4, hh = ii & 15, h = t * 16 + hh;
    float a = b1[h];
#pragma unroll
    for (int d = 0; d < 6; ++d) a += x0[(b0 + r) * 6 + d] * W1[h * 6 + d];
    y_st[p] = a;
  }
  __syncthreads();

  int phase = 0;
#pragma unroll 1
  for (int step = 0; step < NSTEPS; ++step) {
#pragma unroll 1
    for (int sub = 0; sub < 2; ++sub) {
      const int jint = sub ? step : (step > 0 ? step - 1 : 0);
      const int lsb = jint & 1;

      if (sub == 0) {
        for (int e = tid; e < BT * 21; e += NTH) {
          int r = e / 21, l = e - r * 21;
          LSF[step & 1][l][r] = logsig[((size_t)(b0 + r) * NI + step) * 22 + 1 + l];
        }
      }

      // ---- GEMM1 (redundant): v1 = relu(y @ W_vf1^T + b_vf1)
      {
        s16x8 ay[2][4];
#pragma unroll
        for (int m = 0; m < 2; ++m)
#pragma unroll
          for (int kk = 0; kk < 4; ++kk)
            ay[m][kk] = *(const s16x8*)&YB[m * 16 + c][kk * 32 + kg * 8];
        f32x4 p1[2][4];
#pragma unroll
        for (int m = 0; m < 2; ++m)
#pragma unroll
          for (int n = 0; n < 4; ++n) {
            f32x4 p = MFMA_BF16(ay[m][0], w1r[n][0], zf);
            p = MFMA_BF16(ay[m][1], w1r[n][1], p);
            p = MFMA_BF16(ay[m][2], w1r[n][2], p);
            p = MFMA_BF16(ay[m][3], w1r[n][3], p);
            p1[m][n] = p;
          }
#pragma unroll
        for (int m = 0; m < 2; ++m)
#pragma unroll
          for (int n = 0; n < 4; ++n)
#pragma unroll
            for (int q = 0; q < 4; ++q)
              V1R[m * 16 + kg * 4 + q][wv * 64 + n * 16 + c] =
                  bf16u(fmaxf(p1[m][n][q] + bv1[n], 0.f));
      }
      __syncthreads();

      // ---- GEMM2 (redundant): v2 = tanh(v1 @ W_vf2^T + b_vf2), quantize i8 hi/lo
#pragma unroll
      for (int m = 0; m < 2; ++m) {
        s16x8 av[8];
#pragma unroll
        for (int kk = 0; kk < 8; ++kk)
          av[kk] = *(const s16x8*)&V1R[m * 16 + c][kk * 32 + kg * 8];
        f32x4 p2[4];
#pragma unroll
        for (int n = 0; n < 4; ++n) {
          f32x4 p = MFMA_BF16(av[0], w2r[n][0], zf);
#pragma unroll
          for (int kk = 1; kk < 8; ++kk) p = MFMA_BF16(av[kk], w2r[n][kk], p);
          p2[n] = p;
        }
#pragma unroll
        for (int n = 0; n < 4; ++n)
#pragma unroll
          for (int q = 0; q < 4; ++q) {
            float x = p2[n][q] + bv2[n];
            float e2 = __expf(2.f * x);
            float t127 = fmaf(-254.f, __builtin_amdgcn_rcpf(e2 + 1.f), 127.f);  // 127*tanh
            float qh = rintf(t127);
            float ql = rintf((t127 - qh) * 254.f);
            int bo = ((m * 4 + wv) * 64 + n * 16 + kg * 4 + q) * 16 + c;  // frag-linear
            V2QH[bo] = (signed char)(int)qh;
            V2QL[bo] = (signed char)(int)ql;
          }
      }
      __syncthreads();

      // ---- GEMM3 (own 16-h slice, LDS-resident i8 Wm): wave owns contiguous l-range
      {
        i32x4 aih[2][4], ail[2][4];
#pragma unroll
        for (int m = 0; m < 2; ++m)
#pragma unroll
          for (int kk = 0; kk < 4; ++kk) {
            aih[m][kk] = *(const i32x4*)&V2QH[((m * 4 + kk) * 64 + lane) * 16];
            ail[m][kk] = *(const i32x4*)&V2QL[((m * 4 + kk) * 64 + lane) * 16];
          }
        f32x4 acc0 = zf, acc1 = zf;
        const int lb = wv ? (1 + 5 * wv) : 0;   // {0,6,11,16}
        const int nl = wv ? 5 : 6;
#pragma unroll 1
        for (int li = 0; li < nl; ++li) {
          int l = lb + li;
          const i32x4* bp = (const i32x4*)WmL + l * 256 + lane;
          i32x4 bq0 = bp[0], bq1 = bp[64], bq2 = bp[128], bq3 = bp[192];
          i32x4 PH = MFMA_I8(aih[0][0], bq0, zi);
          PH = MFMA_I8(aih[0][1], bq1, PH);
          PH = MFMA_I8(aih[0][2], bq2, PH);
          PH = MFMA_I8(aih[0][3], bq3, PH);
          i32x4 PL = MFMA_I8(ail[0][0], bq0, zi);
          PL = MFMA_I8(ail[0][1], bq1, PL);
          PL = MFMA_I8(ail[0][2], bq2, PL);
          PL = MFMA_I8(ail[0][3], bq3, PL);
          f32x4 ls4 = *(const f32x4*)&LSF[lsb][l][kg * 4];
#pragma unroll
          for (int q = 0; q < 4; ++q)
            acc0[q] += ls4[q] * ((float)PH[q] + (float)PL[q] * 0.003937007874f);
          PH = MFMA_I8(aih[1][0], bq0, zi);
          PH = MFMA_I8(aih[1][1], bq1, PH);
          PH = MFMA_I8(aih[1][2], bq2, PH);
          PH = MFMA_I8(aih[1][3], bq3, PH);
          PL = MFMA_I8(ail[1][0], bq0, zi);
          PL = MFMA_I8(ail[1][1], bq1, PL);
          PL = MFMA_I8(ail[1][2], bq2, PL);
          PL = MFMA_I8(ail[1][3], bq3, PL);
          f32x4 ls4b = *(const f32x4*)&LSF[lsb][l][16 + kg * 4];
#pragma unroll
          for (int q = 0; q < 4; ++q)
            acc1[q] += ls4b[q] * ((float)PH[q] + (float)PL[q] * 0.003937007874f);
        }
#pragma unroll
        for (int q = 0; q < 4; ++q) {
          part[wv][0][kg * 4 + q][c] = acc0[q];
          part[wv][1][kg * 4 + q][c] = acc1[q];
        }
      }
      __syncthreads();

      // ---- reduce + bm + Heun + exchange write (thread owns 2 elements)
#pragma unroll
      for (int p = 0; p < 2; ++p) {
        int ii = p * NTH + tid;
        int r = ii >> 4, hh = ii & 15, m = r >> 4, rr = r & 15;
        float s = part[0][m][rr][hh] + part[1][m][rr][hh] +
                  part[2][m][rr][hh] + part[3][m][rr][hh];
        float bmd = 0.f;
#pragma unroll 3
        for (int l = 0; l < 21; ++l) bmd += LSF[lsb][l][r] * bmL[l * 16 + hh];
        float raw = scL[hh] * s + bmd;
        float yn;
        if (sub == 0) { yp_st[p] = y_st[p] + 0.5f * raw; yn = y_st[p] + raw; }
        else          { y_st[p] = yp_st[p] + 0.5f * raw; yn = y_st[p]; }
        unsigned vv = bf16u(yn);
        unsigned up = (unsigned)__shfl_down((int)vv, 1);
        if (!(hh & 1)) {
          unsigned packed = vv | (up << 16);
          __hip_atomic_store(&ybuf[((phase & 1) * NG + g) * 2048 + t * 256 + r * 8 + (hh >> 1)],
                             packed, __ATOMIC_RELAXED, __HIP_MEMORY_SCOPE_AGENT);
        }
      }
      __syncthreads();  // drains payload stores (vmcnt) before epoch release
      if (tid == 0)
        __hip_atomic_store(myep, (unsigned)(phase + 1), __ATOMIC_RELAXED, __HIP_MEMORY_SCOPE_AGENT);
      if (wv == 0) {  // lanes 0..7 watch the 8 epochs
        unsigned tgt = (unsigned)(phase + 1);
        for (int sp = 0; sp < 50000; ++sp) {
          unsigned e2 = tgt;
          if (lane < 8)
            e2 = __hip_atomic_load(&epk[(g * 8 + lane) * 16], __ATOMIC_RELAXED, __HIP_MEMORY_SCOPE_AGENT);
          if (__all((int)(e2 >= tgt))) break;
        }
      }
      __syncthreads();
      asm volatile("" ::: "memory");
      {  // rebuild full YB from the 8 slices
        const unsigned* srcb = ybuf + ((phase & 1) * NG + g) * 2048;
        for (int e = tid; e < 2048; e += NTH) {
          unsigned pv = __hip_atomic_load(&srcb[e], __ATOMIC_RELAXED, __HIP_MEMORY_SCOPE_AGENT);
          int tsl = e >> 8, id2 = e & 255, rr = id2 >> 3, hp = id2 & 7;
          *(unsigned*)&YB[rr][tsl * 16 + hp * 2] = pv;
        }
      }
      __syncthreads();
      ++phase;
    }
  }

  // ---- logits + softmax (group lead only)
  if (t == 0) {
    for (int e = tid; e < BT * 10; e += NTH) {
      int r = e / 10, cc = e - r * 10;
      float a = b2[cc];
#pragma unroll 4
      for (int h = 0; h < H; ++h) a += b2f(YB[r][h]) * W2[cc * H + h];
      LG[r][cc] = a;
    }
    __syncthreads();
    if (tid < BT) {
      float mx = -1e30f;
#pragma unroll
      for (int cc = 0; cc < 10; ++cc) mx = fmaxf(mx, LG[tid][cc]);
      float ex[10]; float s = 0.f;
#pragma unroll
      for (int cc = 0; cc < 10; ++cc) { ex[cc] = expf(LG[tid][cc] - mx); s += ex[cc]; }
      float inv = 1.f / s;
#pragma unroll
      for (int cc = 0; cc < 10; ++cc) out[(b0 + tid) * 10 + cc] = ex[cc] * inv;
    }
  }
}

extern "C" void kernel_launch(void* const* d_in, const int* in_sizes, int n_in,
                              void* d_out, int out_size, void* d_ws, size_t ws_size,
                              hipStream_t stream) {
  (void)in_sizes; (void)n_in; (void)out_size; (void)ws_size;
  const float* logsig = (const float*)d_in[1];
  const float* x0     = (const float*)d_in[2];
  const float* Wvf1   = (const float*)d_in[3];
  const float* bvf1   = (const float*)d_in[4];
  const float* Wvf2   = (const float*)d_in[5];
  const float* bvf2   = (const float*)d_in[6];
  const float* Wm     = (const float*)d_in[7];
  const float* bmv    = (const float*)d_in[8];
  const float* W1     = (const float*)d_in[9];
  const float* b1     = (const float*)d_in[10];
  const float* W2     = (const float*)d_in[11];
  const float* b2     = (const float*)d_in[12];
  char* ws = (char*)d_ws;

  prep_scales<<<128, NTH, 0, stream>>>(Wm, ws);
  prep_pack<<<3083, NTH, 0, stream>>>(Wvf1, Wvf2, Wm, bmv, ws);
  rde_main<<<NWG, NTH, 0, stream>>>(logsig, x0, W1, b1, bvf1, bvf2, W2, b2, ws,
                                    (float*)d_out);
}

// Round 6
// 948.868 us; speedup vs baseline: 1.7056x; 1.1732x over previous
//
#include <hip/hip_runtime.h>
#include <hip/hip_bf16.h>

typedef float f32x4 __attribute__((ext_vector_type(4)));
typedef int   i32x4 __attribute__((ext_vector_type(4)));
typedef short s16x8 __attribute__((ext_vector_type(8)));
typedef unsigned short u16;

#define NG 32        // groups
#define BT 32        // batch rows per group
#define NWG 256      // 32 groups x 8 WGs (h-split by 16)
#define NTH 512      // threads per WG (8 waves, 2/SIMD)
#define PREPTH 256
#define H 128
#define VW 256
#define NI 64
#define NSTEPS 64

// ws BYTE layout:
#define OFF_FRAG16 0        // u16 frags: W1 (32768 u16) + W2 (65536 u16) = 196608 B
#define OFF_WMQ    196608   // i8 frags [slice8][l21][kk4][lane64][16] = 688128 B
#define OFF_BMF    884736   // f32 [slice8][l21][hh16] = 10752 B
#define OFF_SCF    895488   // f32[128] dequant scale (max_h/127^2)
#define OFF_SINV   896000   // f32[128] pack scale (127/max_h)
#define OFF_YBUF   896512   // u32 [32][4096]: {tag16|bf16} per (r,h) = 524288 B
#define YBUF_BYTES 524288

#define MFMA_BF16(a,b,c) __builtin_amdgcn_mfma_f32_16x16x32_bf16(a,b,c,0,0,0)
#define MFMA_I8(a,b,c)   __builtin_amdgcn_mfma_i32_16x16x64_i8(a,b,c,0,0,0)

__device__ __forceinline__ u16 bf16u(float f) {
  union { float f; unsigned u; } x; x.f = f;
  return (u16)((x.u + 0x7fffu + ((x.u >> 16) & 1u)) >> 16);  // RNE
}
__device__ __forceinline__ float b2f(u16 u) {
  union { unsigned u; float f; } x; x.u = ((unsigned)u) << 16;
  return x.f;
}

// -------- prep 1: per-h max of |Wm| -> scales --------
__global__ void prep_scales(const float* __restrict__ Wm, char* __restrict__ ws) {
  __shared__ float red[4];
  const int tid = threadIdx.x;
  const int h = blockIdx.x;
  float m = 0.f;
  for (int i = tid; i < 21 * VW; i += PREPTH) m = fmaxf(m, fabsf(Wm[h * 21 * VW + i]));
  for (int off = 32; off > 0; off >>= 1) m = fmaxf(m, __shfl_down(m, off));
  if ((tid & 63) == 0) red[tid >> 6] = m;
  __syncthreads();
  if (tid == 0) {
    m = fmaxf(fmaxf(red[0], red[1]), fmaxf(red[2], red[3]));
    m = fmaxf(m, 1e-20f);
    ((float*)(ws + OFF_SCF))[h]  = m / 16129.f;   // max/(127*127)
    ((float*)(ws + OFF_SINV))[h] = 127.f / m;
  }
}

// -------- prep 2: pack W1/W2 bf16 frags, Wm i8 frags, bm slices --------
__global__ void prep_pack(const float* __restrict__ Wvf1, const float* __restrict__ Wvf2,
                          const float* __restrict__ Wm, const float* __restrict__ bmv,
                          char* __restrict__ ws) {
  int idx = blockIdx.x * blockDim.x + threadIdx.x;
  if (idx < 98304) {
    u16* w16 = (u16*)(ws + OFF_FRAG16);
    float val;
    if (idx < 32768) {
      int e = idx;
      int j = e & 7, ln = (e >> 3) & 63, nt = (e >> 9) & 15, kk = e >> 13;
      val = Wvf1[(nt * 16 + (ln & 15)) * H + kk * 32 + (ln >> 4) * 8 + j];
    } else {
      int e = idx - 32768;
      int j = e & 7, ln = (e >> 3) & 63, nt = (e >> 9) & 15, kk = e >> 13;
      val = Wvf2[(nt * 16 + (ln & 15)) * VW + kk * 32 + (ln >> 4) * 8 + j];
    }
    w16[idx] = bf16u(val);
  } else if (idx < 98304 + 688128) {
    int b = idx - 98304;
    int j = b & 15, lane = (b >> 4) & 63, kk = (b >> 10) & 3, rem = b >> 12;
    int l = rem % 21, nt = rem / 21;
    int h = nt * 16 + (lane & 15);
    int w = kk * 64 + (lane >> 4) * 16 + j;
    float sinv = ((const float*)(ws + OFF_SINV))[h];
    float val = Wm[(size_t)(h * 21 + l) * VW + w];
    int q = (int)lrintf(val * sinv);
    q = min(127, max(-127, q));
    ((signed char*)(ws + OFF_WMQ))[b] = (signed char)q;
  } else if (idx < 98304 + 688128 + 2688) {
    int b = idx - (98304 + 688128);
    int hh = b & 15, rem = b >> 4;
    int l = rem % 21, nt = rem / 21;
    ((float*)(ws + OFF_BMF))[b] = bmv[(nt * 16 + hh) * 21 + l];
  }
}

// -------- main persistent kernel --------
__global__ __launch_bounds__(NTH, 1) void rde_main(
    const float* __restrict__ logsig, const float* __restrict__ x0,
    const float* __restrict__ W1, const float* __restrict__ b1,
    const float* __restrict__ bvf1, const float* __restrict__ bvf2,
    const float* __restrict__ W2, const float* __restrict__ b2,
    char* __restrict__ ws, float* __restrict__ out) {
  __shared__ __align__(16) signed char WmL[86016];     // i8 Wm slice, frag-linear
  __shared__ __align__(16) u16   YB [BT][H + 8];       // bf16 y (full)
  __shared__ __align__(16) u16   V1R[BT][VW + 8];      // bf16 relu(v1)
  __shared__ __align__(16) signed char V2QH[8192];     // i8 v2 hi, frag-linear
  __shared__ __align__(16) signed char V2QL[8192];     // i8 v2 lo (residual*254)
  __shared__ __align__(16) float LSF[2][21][BT];       // f32 ls, parity ping-pong
  __shared__ __align__(16) float part[4][2][16][17];   // [l-quarter][m-tile] partials
  __shared__ __align__(16) float bmL[336];             // bm slice [l][hh]
  __shared__ float scL[16];
  __shared__ float LG[BT][10];

  const int tid = threadIdx.x;
  const int lane = tid & 63;
  const int wv = tid >> 6;     // 0..7
  const int c = lane & 15;
  const int kg = lane >> 4;
  const int bid = blockIdx.x;
  const int g = (bid & 7) * 4 + (bid >> 6);   // 0..31 (group members share bid%8 -> XCD heuristic)
  const int t = (bid >> 3) & 7;               // h-slice 0..7
  const int b0 = g * BT;
  unsigned* __restrict__ ybuf = (unsigned*)(ws + OFF_YBUF);
  const s16x8* __restrict__ fr16 = (const s16x8*)(ws + OFF_FRAG16);
  const f32x4 zf = {0.f, 0.f, 0.f, 0.f};
  const i32x4 zi = {0, 0, 0, 0};

  // persistent register weights: wave handles n-tiles {2wv, 2wv+1}
  s16x8 w1r[2][4], w2r[2][8];
#pragma unroll
  for (int n = 0; n < 2; ++n) {
#pragma unroll
    for (int kk = 0; kk < 4; ++kk) w1r[n][kk] = fr16[(kk * 16 + wv * 2 + n) * 64 + lane];
#pragma unroll
    for (int kk = 0; kk < 8; ++kk) w2r[n][kk] = fr16[4096 + (kk * 16 + wv * 2 + n) * 64 + lane];
  }
  float bv1[2], bv2[2];
#pragma unroll
  for (int n = 0; n < 2; ++n) {
    bv1[n] = bvf1[wv * 32 + n * 16 + c];
    bv2[n] = bvf2[wv * 32 + n * 16 + c];
  }

  // Wm slice -> LDS (once)
  {
    const i32x4* wsrc = (const i32x4*)(ws + OFF_WMQ + t * 86016);
    i32x4* wdst = (i32x4*)WmL;
    for (int e = tid; e < 5376; e += NTH) wdst[e] = wsrc[e];
  }
  if (tid < 16) scL[tid] = ((const float*)(ws + OFF_SCF))[t * 16 + tid];
  for (int e = tid; e < 336; e += NTH) bmL[e] = ((const float*)(ws + OFF_BMF))[t * 336 + e];

  // y0 = x0 @ W1^T + b1 (full YB cooperatively + own f32 element)
  for (int e = tid; e < BT * H; e += NTH) {
    int r = e >> 7, h = e & 127;
    float a = b1[h];
#pragma unroll
    for (int d = 0; d < 6; ++d) a += x0[(b0 + r) * 6 + d] * W1[h * 6 + d];
    YB[r][h] = bf16u(a);
  }
  float y_st, yp_st = 0.f;
  {
    int r = tid >> 4, hh = tid & 15, h = t * 16 + hh;
    float a = b1[h];
#pragma unroll
    for (int d = 0; d < 6; ++d) a += x0[(b0 + r) * 6 + d] * W1[h * 6 + d];
    y_st = a;
  }
  __syncthreads();

  int phase = 0;
#pragma unroll 1
  for (int step = 0; step < NSTEPS; ++step) {
#pragma unroll 1
    for (int sub = 0; sub < 2; ++sub) {
      const int jint = sub ? step : (step > 0 ? step - 1 : 0);
      const int lsb = jint & 1;

      if (sub == 0) {
        for (int e = tid; e < BT * 21; e += NTH) {
          int r = e / 21, l = e - r * 21;
          LSF[step & 1][l][r] = logsig[((size_t)(b0 + r) * NI + step) * 22 + 1 + l];
        }
      }

      // ---- GEMM1 (redundant): v1 = relu(y @ W_vf1^T + b_vf1); wave: 2 n-tiles x 2 m-tiles
      {
        s16x8 ay[2][4];
#pragma unroll
        for (int m = 0; m < 2; ++m)
#pragma unroll
          for (int kk = 0; kk < 4; ++kk)
            ay[m][kk] = *(const s16x8*)&YB[m * 16 + c][kk * 32 + kg * 8];
#pragma unroll
        for (int m = 0; m < 2; ++m)
#pragma unroll
          for (int n = 0; n < 2; ++n) {
            f32x4 p = MFMA_BF16(ay[m][0], w1r[n][0], zf);
            p = MFMA_BF16(ay[m][1], w1r[n][1], p);
            p = MFMA_BF16(ay[m][2], w1r[n][2], p);
            p = MFMA_BF16(ay[m][3], w1r[n][3], p);
#pragma unroll
            for (int q = 0; q < 4; ++q)
              V1R[m * 16 + kg * 4 + q][wv * 32 + n * 16 + c] =
                  bf16u(fmaxf(p[q] + bv1[n], 0.f));
          }
      }
      __syncthreads();

      // ---- GEMM2 (redundant): v2 = tanh(v1 @ W_vf2^T + b_vf2), quantize i8 hi/lo
#pragma unroll
      for (int m = 0; m < 2; ++m) {
        s16x8 av[8];
#pragma unroll
        for (int kk = 0; kk < 8; ++kk)
          av[kk] = *(const s16x8*)&V1R[m * 16 + c][kk * 32 + kg * 8];
#pragma unroll
        for (int n = 0; n < 2; ++n) {
          f32x4 p = MFMA_BF16(av[0], w2r[n][0], zf);
#pragma unroll
          for (int kk = 1; kk < 8; ++kk) p = MFMA_BF16(av[kk], w2r[n][kk], p);
#pragma unroll
          for (int q = 0; q < 4; ++q) {
            float x = p[q] + bv2[n];
            float e2 = __expf(2.f * x);
            float t127 = fmaf(-254.f, __builtin_amdgcn_rcpf(e2 + 1.f), 127.f);  // 127*tanh
            float qh = rintf(t127);
            float ql = rintf((t127 - qh) * 254.f);
            int bo = ((m * 4 + (wv >> 1)) * 64 + ((wv & 1) * 2 + n) * 16 + kg * 4 + q) * 16 + c;
            V2QH[bo] = (signed char)(int)qh;
            V2QL[bo] = (signed char)(int)ql;
          }
        }
      }
      __syncthreads();

      // ---- GEMM3 (own 16-h slice, LDS-resident i8 Wm): wave = (m-tile, l-quarter)
      {
        const int m3 = wv & 1;
        const int jq = wv >> 1;
        i32x4 aih[4], ail[4];
#pragma unroll
        for (int kk = 0; kk < 4; ++kk) {
          aih[kk] = *(const i32x4*)&V2QH[((m3 * 4 + kk) * 64 + lane) * 16];
          ail[kk] = *(const i32x4*)&V2QL[((m3 * 4 + kk) * 64 + lane) * 16];
        }
        f32x4 acc = zf;
        const int lb = jq ? (1 + 5 * jq) : 0;   // {0,6,11,16}
        const int nl = jq ? 5 : 6;
#pragma unroll 1
        for (int li = 0; li < nl; ++li) {
          int l = lb + li;
          const i32x4* bp = (const i32x4*)WmL + l * 256 + lane;
          i32x4 bq0 = bp[0], bq1 = bp[64], bq2 = bp[128], bq3 = bp[192];
          i32x4 PH = MFMA_I8(aih[0], bq0, zi);
          PH = MFMA_I8(aih[1], bq1, PH);
          PH = MFMA_I8(aih[2], bq2, PH);
          PH = MFMA_I8(aih[3], bq3, PH);
          i32x4 PL = MFMA_I8(ail[0], bq0, zi);
          PL = MFMA_I8(ail[1], bq1, PL);
          PL = MFMA_I8(ail[2], bq2, PL);
          PL = MFMA_I8(ail[3], bq3, PL);
          f32x4 ls4 = *(const f32x4*)&LSF[lsb][l][m3 * 16 + kg * 4];
#pragma unroll
          for (int q = 0; q < 4; ++q)
            acc[q] += ls4[q] * ((float)PH[q] + (float)PL[q] * 0.003937007874f);
        }
#pragma unroll
        for (int q = 0; q < 4; ++q) part[jq][m3][kg * 4 + q][c] = acc[q];
      }
      __syncthreads();

      // ---- reduce + bm + Heun + tagged exchange (thread owns element (r, t*16+hh))
      {
        int r = tid >> 4, hh = tid & 15, m = r >> 4, rr = r & 15;
        float s = part[0][m][rr][hh] + part[1][m][rr][hh] +
                  part[2][m][rr][hh] + part[3][m][rr][hh];
        float bmd = 0.f;
#pragma unroll 3
        for (int l = 0; l < 21; ++l) bmd += LSF[lsb][l][r] * bmL[l * 16 + hh];
        float raw = scL[hh] * s + bmd;
        float yn;
        if (sub == 0) { yp_st = y_st + 0.5f * raw; yn = y_st + raw; }
        else          { y_st = yp_st + 0.5f * raw; yn = y_st; }
        unsigned v = ((unsigned)(phase + 1) << 16) | (unsigned)bf16u(yn);
        __hip_atomic_store(&ybuf[g * 4096 + r * 128 + t * 16 + hh], v,
                           __ATOMIC_RELAXED, __HIP_MEMORY_SCOPE_AGENT);
      }
      // ---- rebuild full YB: poll tag-in-word (atomic word => tag/data consistent)
      {
        const unsigned tg = (unsigned)(phase + 1);
        const unsigned* srcb = ybuf + g * 4096;
        unsigned v0, v1, v2, v3, v4, v5, v6, v7;
#pragma unroll 1
        for (int sp = 0; sp < 60000; ++sp) {
          v0 = __hip_atomic_load(&srcb[0 * NTH + tid], __ATOMIC_RELAXED, __HIP_MEMORY_SCOPE_AGENT);
          v1 = __hip_atomic_load(&srcb[1 * NTH + tid], __ATOMIC_RELAXED, __HIP_MEMORY_SCOPE_AGENT);
          v2 = __hip_atomic_load(&srcb[2 * NTH + tid], __ATOMIC_RELAXED, __HIP_MEMORY_SCOPE_AGENT);
          v3 = __hip_atomic_load(&srcb[3 * NTH + tid], __ATOMIC_RELAXED, __HIP_MEMORY_SCOPE_AGENT);
          v4 = __hip_atomic_load(&srcb[4 * NTH + tid], __ATOMIC_RELAXED, __HIP_MEMORY_SCOPE_AGENT);
          v5 = __hip_atomic_load(&srcb[5 * NTH + tid], __ATOMIC_RELAXED, __HIP_MEMORY_SCOPE_AGENT);
          v6 = __hip_atomic_load(&srcb[6 * NTH + tid], __ATOMIC_RELAXED, __HIP_MEMORY_SCOPE_AGENT);
          v7 = __hip_atomic_load(&srcb[7 * NTH + tid], __ATOMIC_RELAXED, __HIP_MEMORY_SCOPE_AGENT);
          unsigned mn = v0 >> 16;
          mn = min(mn, v1 >> 16); mn = min(mn, v2 >> 16); mn = min(mn, v3 >> 16);
          mn = min(mn, v4 >> 16); mn = min(mn, v5 >> 16); mn = min(mn, v6 >> 16);
          mn = min(mn, v7 >> 16);
          if (mn == tg) break;   // tags only ever increase 1..128; poison/zero never matches
        }
        int e0 = tid;
        YB[(e0) >> 7][(e0) & 127]                    = (u16)(v0 & 0xffffu);
        YB[(e0 + 512) >> 7][(e0 + 512) & 127]        = (u16)(v1 & 0xffffu);
        YB[(e0 + 1024) >> 7][(e0 + 1024) & 127]      = (u16)(v2 & 0xffffu);
        YB[(e0 + 1536) >> 7][(e0 + 1536) & 127]      = (u16)(v3 & 0xffffu);
        YB[(e0 + 2048) >> 7][(e0 + 2048) & 127]      = (u16)(v4 & 0xffffu);
        YB[(e0 + 2560) >> 7][(e0 + 2560) & 127]      = (u16)(v5 & 0xffffu);
        YB[(e0 + 3072) >> 7][(e0 + 3072) & 127]      = (u16)(v6 & 0xffffu);
        YB[(e0 + 3584) >> 7][(e0 + 3584) & 127]      = (u16)(v7 & 0xffffu);
      }
      __syncthreads();
      ++phase;
    }
  }

  // ---- logits + softmax (group lead only)
  if (t == 0) {
    for (int e = tid; e < BT * 10; e += NTH) {
      int r = e / 10, cc = e - r * 10;
      float a = b2[cc];
#pragma unroll 4
      for (int h = 0; h < H; ++h) a += b2f(YB[r][h]) * W2[cc * H + h];
      LG[r][cc] = a;
    }
    __syncthreads();
    if (tid < BT) {
      float mx = -1e30f;
#pragma unroll
      for (int cc = 0; cc < 10; ++cc) mx = fmaxf(mx, LG[tid][cc]);
      float ex[10]; float s = 0.f;
#pragma unroll
      for (int cc = 0; cc < 10; ++cc) { ex[cc] = expf(LG[tid][cc] - mx); s += ex[cc]; }
      float inv = 1.f / s;
#pragma unroll
      for (int cc = 0; cc < 10; ++cc) out[(b0 + tid) * 10 + cc] = ex[cc] * inv;
    }
  }
}

extern "C" void kernel_launch(void* const* d_in, const int* in_sizes, int n_in,
                              void* d_out, int out_size, void* d_ws, size_t ws_size,
                              hipStream_t stream) {
  (void)in_sizes; (void)n_in; (void)out_size; (void)ws_size;
  const float* logsig = (const float*)d_in[1];
  const float* x0     = (const float*)d_in[2];
  const float* Wvf1   = (const float*)d_in[3];
  const float* bvf1   = (const float*)d_in[4];
  const float* Wvf2   = (const float*)d_in[5];
  const float* bvf2   = (const float*)d_in[6];
  const float* Wm     = (const float*)d_in[7];
  const float* bmv    = (const float*)d_in[8];
  const float* W1     = (const float*)d_in[9];
  const float* b1     = (const float*)d_in[10];
  const float* W2     = (const float*)d_in[11];
  const float* b2     = (const float*)d_in[12];
  char* ws = (char*)d_ws;

  prep_scales<<<128, PREPTH, 0, stream>>>(Wm, ws);
  prep_pack<<<3083, PREPTH, 0, stream>>>(Wvf1, Wvf2, Wm, bmv, ws);
  hipMemsetAsync(ws + OFF_YBUF, 0, YBUF_BYTES, stream);  // kill stale tags each call
  rde_main<<<NWG, NTH, 0, stream>>>(logsig, x0, W1, b1, bvf1, bvf2, W2, b2, ws,
                                    (float*)d_out);
}

// Round 7
// 721.545 us; speedup vs baseline: 2.2430x; 1.3151x over previous
//
#include <hip/hip_runtime.h>
#include <hip/hip_bf16.h>

typedef float f32x4 __attribute__((ext_vector_type(4)));
typedef int   i32x4 __attribute__((ext_vector_type(4)));
typedef short s16x8 __attribute__((ext_vector_type(8)));
typedef unsigned short u16;

#define NGP 32       // group-pairs; each = 2 tiles x 16 rows = 32 batch rows
#define BT 16        // rows per tile
#define NWG 256      // 32 pairs x 8 h-slices
#define NTH 512      // 8 waves
#define PREPTH 256
#define H 128
#define VW 256
#define NI 64
#define NSTEPS 64

// ws BYTE layout:
#define OFF_FRAG16 0        // u16 frags: W1 (32768 u16) + W2 (65536 u16) = 196608 B
#define OFF_WMQ    196608   // i8 frags [slice8][l21][kk4][lane64][16] = 688128 B
#define OFF_BMF    884736   // f32 [slice8][l21][hh16] = 10752 B
#define OFF_SCF    895488   // f32[128]
#define OFF_SINV   896000   // f32[128]
#define OFF_YBUF   896512   // u32 [64 grp16][2 parity][16 r][128 h] = 1 MB
#define YBUF_BYTES 1048576

#define MFMA_BF16(a,b,c) __builtin_amdgcn_mfma_f32_16x16x32_bf16(a,b,c,0,0,0)
#define MFMA_I8(a,b,c)   __builtin_amdgcn_mfma_i32_16x16x64_i8(a,b,c,0,0,0)

template<int N> struct IC { static constexpr int v = N; };

__device__ __forceinline__ u16 bf16u(float f) {
  union { float f; unsigned u; } x; x.f = f;
  return (u16)((x.u + 0x7fffu + ((x.u >> 16) & 1u)) >> 16);  // RNE
}
__device__ __forceinline__ float b2f(u16 u) {
  union { unsigned u; float f; } x; x.u = ((unsigned)u) << 16;
  return x.f;
}

// -------- prep 1: per-h max of |Wm| -> scales --------
__global__ void prep_scales(const float* __restrict__ Wm, char* __restrict__ ws) {
  __shared__ float red[4];
  const int tid = threadIdx.x;
  const int h = blockIdx.x;
  float m = 0.f;
  for (int i = tid; i < 21 * VW; i += PREPTH) m = fmaxf(m, fabsf(Wm[h * 21 * VW + i]));
  for (int off = 32; off > 0; off >>= 1) m = fmaxf(m, __shfl_down(m, off));
  if ((tid & 63) == 0) red[tid >> 6] = m;
  __syncthreads();
  if (tid == 0) {
    m = fmaxf(fmaxf(red[0], red[1]), fmaxf(red[2], red[3]));
    m = fmaxf(m, 1e-20f);
    ((float*)(ws + OFF_SCF))[h]  = m / 16129.f;   // max/(127*127)
    ((float*)(ws + OFF_SINV))[h] = 127.f / m;
  }
}

// -------- prep 2: pack W1/W2 bf16 frags, Wm i8 frags, bm slices --------
__global__ void prep_pack(const float* __restrict__ Wvf1, const float* __restrict__ Wvf2,
                          const float* __restrict__ Wm, const float* __restrict__ bmv,
                          char* __restrict__ ws) {
  int idx = blockIdx.x * blockDim.x + threadIdx.x;
  if (idx < 98304) {
    u16* w16 = (u16*)(ws + OFF_FRAG16);
    float val;
    if (idx < 32768) {
      int e = idx;
      int j = e & 7, ln = (e >> 3) & 63, nt = (e >> 9) & 15, kk = e >> 13;
      val = Wvf1[(nt * 16 + (ln & 15)) * H + kk * 32 + (ln >> 4) * 8 + j];
    } else {
      int e = idx - 32768;
      int j = e & 7, ln = (e >> 3) & 63, nt = (e >> 9) & 15, kk = e >> 13;
      val = Wvf2[(nt * 16 + (ln & 15)) * VW + kk * 32 + (ln >> 4) * 8 + j];
    }
    w16[idx] = bf16u(val);
  } else if (idx < 98304 + 688128) {
    int b = idx - 98304;
    int j = b & 15, lane = (b >> 4) & 63, kk = (b >> 10) & 3, rem = b >> 12;
    int l = rem % 21, nt = rem / 21;
    int h = nt * 16 + (lane & 15);
    int w = kk * 64 + (lane >> 4) * 16 + j;
    float sinv = ((const float*)(ws + OFF_SINV))[h];
    float val = Wm[(size_t)(h * 21 + l) * VW + w];
    int q = (int)lrintf(val * sinv);
    q = min(127, max(-127, q));
    ((signed char*)(ws + OFF_WMQ))[b] = (signed char)q;
  } else if (idx < 98304 + 688128 + 2688) {
    int b = idx - (98304 + 688128);
    int hh = b & 15, rem = b >> 4;
    int l = rem % 21, nt = rem / 21;
    ((float*)(ws + OFF_BMF))[b] = bmv[(nt * 16 + hh) * 21 + l];
  }
}

// -------- main persistent kernel: 2-tile staggered pipeline --------
__global__ __launch_bounds__(NTH, 1) void rde_main(
    const float* __restrict__ logsig, const float* __restrict__ x0,
    const float* __restrict__ W1, const float* __restrict__ b1,
    const float* __restrict__ bvf1, const float* __restrict__ bvf2,
    const float* __restrict__ W2, const float* __restrict__ b2,
    char* __restrict__ ws, float* __restrict__ out) {
  __shared__ __align__(16) signed char WmL[86016];    // i8 Wm slice (shared by both tiles)
  __shared__ __align__(16) u16   YB [2][BT][H + 8];   // per-tile bf16 y
  __shared__ __align__(16) u16   V1R[2][BT][VW + 8];
  __shared__ __align__(16) signed char V2QH[2][4096];
  __shared__ __align__(16) signed char V2QL[2][4096];
  __shared__ __align__(16) float LSF[2][2][21][BT];   // [tile][parity][l][r]
  __shared__ __align__(16) float part[2][8][BT][17];  // [tile][wave][r][h]
  __shared__ __align__(16) float bmL[336];
  __shared__ float scL[16];
  __shared__ float LG[32][10];

  const int tid = threadIdx.x;
  const int lane = tid & 63;
  const int wv = tid >> 6;     // 0..7
  const int c = lane & 15;
  const int kg = lane >> 4;
  const int bid = blockIdx.x;
  const int Gp = (bid & 7) * 4 + (bid >> 6);  // 0..31; pair members share bid%8 (XCD heuristic)
  const int t = (bid >> 3) & 7;               // h-slice 0..7
  const int b0 = Gp * 32;
  unsigned* __restrict__ ybuf = (unsigned*)(ws + OFF_YBUF);
  const s16x8* __restrict__ fr16 = (const s16x8*)(ws + OFF_FRAG16);
  const f32x4 zf = {0.f, 0.f, 0.f, 0.f};
  const i32x4 zi = {0, 0, 0, 0};

  // persistent register weights: wave handles n-tiles {2wv, 2wv+1}
  s16x8 w1r[2][4], w2r[2][8];
#pragma unroll
  for (int n = 0; n < 2; ++n) {
#pragma unroll
    for (int kk = 0; kk < 4; ++kk) w1r[n][kk] = fr16[(kk * 16 + wv * 2 + n) * 64 + lane];
#pragma unroll
    for (int kk = 0; kk < 8; ++kk) w2r[n][kk] = fr16[4096 + (kk * 16 + wv * 2 + n) * 64 + lane];
  }
  float bv1[2], bv2[2];
#pragma unroll
  for (int n = 0; n < 2; ++n) {
    bv1[n] = bvf1[wv * 32 + n * 16 + c];
    bv2[n] = bvf2[wv * 32 + n * 16 + c];
  }

  {  // Wm slice -> LDS (once)
    const i32x4* wsrc = (const i32x4*)(ws + OFF_WMQ + t * 86016);
    i32x4* wdst = (i32x4*)WmL;
    for (int e = tid; e < 5376; e += NTH) wdst[e] = wsrc[e];
  }
  if (tid < 16) scL[tid] = ((const float*)(ws + OFF_SCF))[t * 16 + tid];
  for (int e = tid; e < 336; e += NTH) bmL[e] = ((const float*)(ws + OFF_BMF))[t * 336 + e];

  // y0 = x0 @ W1^T + b1 for both tiles
  for (int e = tid; e < 2 * BT * H; e += NTH) {
    int tt = e >> 11, r = (e >> 7) & 15, h = e & 127;
    float a = b1[h];
#pragma unroll
    for (int d = 0; d < 6; ++d) a += x0[(b0 + tt * 16 + r) * 6 + d] * W1[h * 6 + d];
    YB[tt][r][h] = bf16u(a);
  }
  float y_st[2], yp_st[2];
  yp_st[0] = yp_st[1] = 0.f;
  if (tid < 256) {
    int r = tid >> 4, hh = tid & 15, h = t * 16 + hh;
#pragma unroll
    for (int tt = 0; tt < 2; ++tt) {
      float a = b1[h];
#pragma unroll
      for (int d = 0; d < 6; ++d) a += x0[(b0 + tt * 16 + r) * 6 + d] * W1[h * 6 + d];
      y_st[tt] = a;
    }
  } else { y_st[0] = y_st[1] = 0.f; }
  __syncthreads();

  int j = 0;
  auto slot = [&](auto tc) {
    constexpr int TT = decltype(tc)::v;
    const int step_ = j >> 1, sub_ = j & 1;
    const int jint_ = sub_ ? step_ : (step_ > 0 ? step_ - 1 : 0);
    const int lsb_ = jint_ & 1;

    if (sub_ == 0) {
      for (int e = tid; e < BT * 21; e += NTH) {
        int r = e / 21, l = e - r * 21;
        LSF[TT][step_ & 1][l][r] =
            logsig[((size_t)(b0 + TT * 16 + r) * NI + step_) * 22 + 1 + l];
      }
    }

    // ---- GEMM1: v1 = relu(y @ W_vf1^T + b_vf1)
    {
      s16x8 ay0 = *(const s16x8*)&YB[TT][c][0 * 32 + kg * 8];
      s16x8 ay1 = *(const s16x8*)&YB[TT][c][1 * 32 + kg * 8];
      s16x8 ay2 = *(const s16x8*)&YB[TT][c][2 * 32 + kg * 8];
      s16x8 ay3 = *(const s16x8*)&YB[TT][c][3 * 32 + kg * 8];
      f32x4 pA = MFMA_BF16(ay0, w1r[0][0], zf), pB = MFMA_BF16(ay0, w1r[1][0], zf);
      pA = MFMA_BF16(ay1, w1r[0][1], pA);  pB = MFMA_BF16(ay1, w1r[1][1], pB);
      pA = MFMA_BF16(ay2, w1r[0][2], pA);  pB = MFMA_BF16(ay2, w1r[1][2], pB);
      pA = MFMA_BF16(ay3, w1r[0][3], pA);  pB = MFMA_BF16(ay3, w1r[1][3], pB);
#pragma unroll
      for (int q = 0; q < 4; ++q) {
        V1R[TT][kg * 4 + q][wv * 32 + c]      = bf16u(fmaxf(pA[q] + bv1[0], 0.f));
        V1R[TT][kg * 4 + q][wv * 32 + 16 + c] = bf16u(fmaxf(pB[q] + bv1[1], 0.f));
      }
    }
    __syncthreads();

    // ---- GEMM2: v2 = tanh(v1 @ W_vf2^T + b_vf2), quantize i8 hi/lo
    {
      s16x8 av0 = *(const s16x8*)&V1R[TT][c][0 * 32 + kg * 8];
      s16x8 av1 = *(const s16x8*)&V1R[TT][c][1 * 32 + kg * 8];
      s16x8 av2 = *(const s16x8*)&V1R[TT][c][2 * 32 + kg * 8];
      s16x8 av3 = *(const s16x8*)&V1R[TT][c][3 * 32 + kg * 8];
      s16x8 av4 = *(const s16x8*)&V1R[TT][c][4 * 32 + kg * 8];
      s16x8 av5 = *(const s16x8*)&V1R[TT][c][5 * 32 + kg * 8];
      s16x8 av6 = *(const s16x8*)&V1R[TT][c][6 * 32 + kg * 8];
      s16x8 av7 = *(const s16x8*)&V1R[TT][c][7 * 32 + kg * 8];
      f32x4 pA = MFMA_BF16(av0, w2r[0][0], zf), pB = MFMA_BF16(av0, w2r[1][0], zf);
      pA = MFMA_BF16(av1, w2r[0][1], pA);  pB = MFMA_BF16(av1, w2r[1][1], pB);
      pA = MFMA_BF16(av2, w2r[0][2], pA);  pB = MFMA_BF16(av2, w2r[1][2], pB);
      pA = MFMA_BF16(av3, w2r[0][3], pA);  pB = MFMA_BF16(av3, w2r[1][3], pB);
      pA = MFMA_BF16(av4, w2r[0][4], pA);  pB = MFMA_BF16(av4, w2r[1][4], pB);
      pA = MFMA_BF16(av5, w2r[0][5], pA);  pB = MFMA_BF16(av5, w2r[1][5], pB);
      pA = MFMA_BF16(av6, w2r[0][6], pA);  pB = MFMA_BF16(av6, w2r[1][6], pB);
      pA = MFMA_BF16(av7, w2r[0][7], pA);  pB = MFMA_BF16(av7, w2r[1][7], pB);
#pragma unroll
      for (int n = 0; n < 2; ++n) {
        f32x4 p = n ? pB : pA;
#pragma unroll
        for (int q = 0; q < 4; ++q) {
          float x = p[q] + bv2[n];
          float e2 = __expf(2.f * x);
          float t127 = fmaf(-254.f, __builtin_amdgcn_rcpf(e2 + 1.f), 127.f);
          float qh = rintf(t127);
          float ql = rintf((t127 - qh) * 254.f);
          int bo = ((wv >> 1) * 64 + ((wv & 1) * 2 + n) * 16 + kg * 4 + q) * 16 + c;
          V2QH[TT][bo] = (signed char)(int)qh;
          V2QL[TT][bo] = (signed char)(int)ql;
        }
      }
    }
    __syncthreads();

    // ---- GEMM3: wave owns l-chunk {3,3,3,3,3,2,2,2}
    {
      i32x4 aih0 = *(const i32x4*)&V2QH[TT][(0 * 64 + lane) * 16];
      i32x4 aih1 = *(const i32x4*)&V2QH[TT][(1 * 64 + lane) * 16];
      i32x4 aih2 = *(const i32x4*)&V2QH[TT][(2 * 64 + lane) * 16];
      i32x4 aih3 = *(const i32x4*)&V2QH[TT][(3 * 64 + lane) * 16];
      i32x4 ail0 = *(const i32x4*)&V2QL[TT][(0 * 64 + lane) * 16];
      i32x4 ail1 = *(const i32x4*)&V2QL[TT][(1 * 64 + lane) * 16];
      i32x4 ail2 = *(const i32x4*)&V2QL[TT][(2 * 64 + lane) * 16];
      i32x4 ail3 = *(const i32x4*)&V2QL[TT][(3 * 64 + lane) * 16];
      const int nl = (wv < 5) ? 3 : 2;
      const int lb = (wv < 5) ? 3 * wv : 15 + 2 * (wv - 5);
      f32x4 acc = zf;
      for (int li = 0; li < nl; ++li) {
        int l = lb + li;
        const i32x4* bp = (const i32x4*)WmL + l * 256 + lane;
        i32x4 bq0 = bp[0], bq1 = bp[64], bq2 = bp[128], bq3 = bp[192];
        i32x4 PH = MFMA_I8(aih0, bq0, zi);
        i32x4 PL = MFMA_I8(ail0, bq0, zi);
        PH = MFMA_I8(aih1, bq1, PH);  PL = MFMA_I8(ail1, bq1, PL);
        PH = MFMA_I8(aih2, bq2, PH);  PL = MFMA_I8(ail2, bq2, PL);
        PH = MFMA_I8(aih3, bq3, PH);  PL = MFMA_I8(ail3, bq3, PL);
        f32x4 ls4 = *(const f32x4*)&LSF[TT][lsb_][l][kg * 4];
#pragma unroll
        for (int q = 0; q < 4; ++q)
          acc[q] += ls4[q] * ((float)PH[q] + (float)PL[q] * 0.003937007874f);
      }
#pragma unroll
      for (int q = 0; q < 4; ++q) part[TT][wv][kg * 4 + q][c] = acc[q];
    }
    __syncthreads();

    // ---- Heun + store (threads 0..255), then all threads poll other tile
    if (tid < 256) {
      int r = tid >> 4, hh = tid & 15;
      float s = ((part[TT][0][r][hh] + part[TT][1][r][hh]) +
                 (part[TT][2][r][hh] + part[TT][3][r][hh])) +
                ((part[TT][4][r][hh] + part[TT][5][r][hh]) +
                 (part[TT][6][r][hh] + part[TT][7][r][hh]));
      float bmd = 0.f;
#pragma unroll
      for (int l = 0; l < 21; ++l) bmd += LSF[TT][lsb_][l][r] * bmL[l * 16 + hh];
      float raw = scL[hh] * s + bmd;
      float yn;
      if (sub_ == 0) { yp_st[TT] = y_st[TT] + 0.5f * raw; yn = y_st[TT] + raw; }
      else           { y_st[TT] = yp_st[TT] + 0.5f * raw; yn = y_st[TT]; }
      unsigned v = ((unsigned)(j + 1) << 16) | (unsigned)bf16u(yn);
      __hip_atomic_store(&ybuf[((Gp * 2 + TT) * 2 + (j & 1)) * 2048 + r * 128 + t * 16 + hh],
                         v, __ATOMIC_RELAXED, __HIP_MEMORY_SCOPE_AGENT);
    }
    {
      const int ptag = (TT == 0) ? j : (j + 1);   // other tile's expected tag
      if (ptag > 0) {
        const unsigned* pb =
            ybuf + ((Gp * 2 + (TT ^ 1)) * 2 + ((ptag - 1) & 1)) * 2048;
        unsigned v0, v1, v2, v3;
#pragma unroll 1
        for (int sp = 0; sp < 60000; ++sp) {
          v0 = __hip_atomic_load(&pb[tid],        __ATOMIC_RELAXED, __HIP_MEMORY_SCOPE_AGENT);
          v1 = __hip_atomic_load(&pb[tid + 512],  __ATOMIC_RELAXED, __HIP_MEMORY_SCOPE_AGENT);
          v2 = __hip_atomic_load(&pb[tid + 1024], __ATOMIC_RELAXED, __HIP_MEMORY_SCOPE_AGENT);
          v3 = __hip_atomic_load(&pb[tid + 1536], __ATOMIC_RELAXED, __HIP_MEMORY_SCOPE_AGENT);
          unsigned mn = min(min(v0 >> 16, v1 >> 16), min(v2 >> 16, v3 >> 16));
          if (mn == (unsigned)ptag) break;
        }
        YB[TT ^ 1][tid >> 7][tid & 127] = (u16)(v0 & 0xffffu);
        YB[TT ^ 1][(tid + 512) >> 7][(tid + 512) & 127] = (u16)(v1 & 0xffffu);
        YB[TT ^ 1][(tid + 1024) >> 7][(tid + 1024) & 127] = (u16)(v2 & 0xffffu);
        YB[TT ^ 1][(tid + 1536) >> 7][(tid + 1536) & 127] = (u16)(v3 & 0xffffu);
      }
    }
    __syncthreads();
  };

#pragma unroll 1
  for (j = 0; j < 2 * NSTEPS; ++j) {
    slot(IC<0>{});
    slot(IC<1>{});
  }

  // ---- final: poll tile1 tag 128 (parity 1), rebuild YB[1]
  {
    const unsigned* pb = ybuf + ((Gp * 2 + 1) * 2 + 1) * 2048;
    unsigned v0, v1, v2, v3;
#pragma unroll 1
    for (int sp = 0; sp < 60000; ++sp) {
      v0 = __hip_atomic_load(&pb[tid],        __ATOMIC_RELAXED, __HIP_MEMORY_SCOPE_AGENT);
      v1 = __hip_atomic_load(&pb[tid + 512],  __ATOMIC_RELAXED, __HIP_MEMORY_SCOPE_AGENT);
      v2 = __hip_atomic_load(&pb[tid + 1024], __ATOMIC_RELAXED, __HIP_MEMORY_SCOPE_AGENT);
      v3 = __hip_atomic_load(&pb[tid + 1536], __ATOMIC_RELAXED, __HIP_MEMORY_SCOPE_AGENT);
      unsigned mn = min(min(v0 >> 16, v1 >> 16), min(v2 >> 16, v3 >> 16));
      if (mn == 128u) break;
    }
    YB[1][tid >> 7][tid & 127] = (u16)(v0 & 0xffffu);
    YB[1][(tid + 512) >> 7][(tid + 512) & 127] = (u16)(v1 & 0xffffu);
    YB[1][(tid + 1024) >> 7][(tid + 1024) & 127] = (u16)(v2 & 0xffffu);
    YB[1][(tid + 1536) >> 7][(tid + 1536) & 127] = (u16)(v3 & 0xffffu);
  }
  __syncthreads();

  // ---- logits + softmax (slice-0 WG of each pair; 32 rows)
  if (t == 0) {
    for (int e = tid; e < 32 * 10; e += NTH) {
      int rr = e / 10, cc = e - rr * 10;
      float a = b2[cc];
#pragma unroll 4
      for (int h = 0; h < H; ++h) a += b2f(YB[rr >> 4][rr & 15][h]) * W2[cc * H + h];
      LG[rr][cc] = a;
    }
    __syncthreads();
    if (tid < 32) {
      float mx = -1e30f;
#pragma unroll
      for (int cc = 0; cc < 10; ++cc) mx = fmaxf(mx, LG[tid][cc]);
      float ex[10]; float s = 0.f;
#pragma unroll
      for (int cc = 0; cc < 10; ++cc) { ex[cc] = expf(LG[tid][cc] - mx); s += ex[cc]; }
      float inv = 1.f / s;
#pragma unroll
      for (int cc = 0; cc < 10; ++cc) out[(b0 + tid) * 10 + cc] = ex[cc] * inv;
    }
  }
}

extern "C" void kernel_launch(void* const* d_in, const int* in_sizes, int n_in,
                              void* d_out, int out_size, void* d_ws, size_t ws_size,
                              hipStream_t stream) {
  (void)in_sizes; (void)n_in; (void)out_size; (void)ws_size;
  const float* logsig = (const float*)d_in[1];
  const float* x0     = (const float*)d_in[2];
  const float* Wvf1   = (const float*)d_in[3];
  const float* bvf1   = (const float*)d_in[4];
  const float* Wvf2   = (const float*)d_in[5];
  const float* bvf2   = (const float*)d_in[6];
  const float* Wm     = (const float*)d_in[7];
  const float* bmv    = (const float*)d_in[8];
  const float* W1     = (const float*)d_in[9];
  const float* b1     = (const float*)d_in[10];
  const float* W2     = (const float*)d_in[11];
  const float* b2     = (const float*)d_in[12];
  char* ws = (char*)d_ws;

  prep_scales<<<128, PREPTH, 0, stream>>>(Wm, ws);
  prep_pack<<<3083, PREPTH, 0, stream>>>(Wvf1, Wvf2, Wm, bmv, ws);
  hipMemsetAsync(ws + OFF_YBUF, 0, YBUF_BYTES, stream);  // kill stale tags each call
  rde_main<<<NWG, NTH, 0, stream>>>(logsig, x0, W1, b1, bvf1, bvf2, W2, b2, ws,
                                    (float*)d_out);
}

// Round 8
// 572.493 us; speedup vs baseline: 2.8270x; 1.2604x over previous
//
#include <hip/hip_runtime.h>
#include <hip/hip_bf16.h>

typedef float f32x4 __attribute__((ext_vector_type(4)));
typedef int   i32x4 __attribute__((ext_vector_type(4)));
typedef short s16x8 __attribute__((ext_vector_type(8)));
typedef unsigned short u16;

#define NGP 32       // group-pairs; each = 2 tiles x 16 rows
#define BT 16        // rows per tile
#define NWG 256      // 32 pairs x 8 h-slices
#define NTH 512      // 8 waves
#define PREPTH 256
#define H 128
#define VW 256
#define NI 64
#define NSTEPS 64

// ws BYTE layout:
#define OFF_FRAG16 0        // u16 frags: W1 (32768 u16) + W2 (65536 u16) = 196608 B
#define OFF_WMQ    196608   // i8 frags [slice8][l21][kk4][lane64][16] = 688128 B
#define OFF_BMF    884736   // f32 [slice8][l21][hh16] = 10752 B
#define OFF_SCF    895488   // f32[128]
#define OFF_SINV   896000   // f32[128]
#define OFF_YBUF   896512   // u32 [64 tile][2 parity][2048] = 1 MB
#define YBUF_BYTES 1048576

#define MFMA_BF16(a,b,c) __builtin_amdgcn_mfma_f32_16x16x32_bf16(a,b,c,0,0,0)
#define MFMA_I8(a,b,c)   __builtin_amdgcn_mfma_i32_16x16x64_i8(a,b,c,0,0,0)

__device__ __forceinline__ u16 bf16u(float f) {
  union { float f; unsigned u; } x; x.f = f;
  return (u16)((x.u + 0x7fffu + ((x.u >> 16) & 1u)) >> 16);  // RNE
}
__device__ __forceinline__ float b2f(u16 u) {
  union { unsigned u; float f; } x; x.u = ((unsigned)u) << 16;
  return x.f;
}

// -------- prep 1: per-h max of |Wm| -> scales --------
__global__ void prep_scales(const float* __restrict__ Wm, char* __restrict__ ws) {
  __shared__ float red[4];
  const int tid = threadIdx.x;
  const int h = blockIdx.x;
  float m = 0.f;
  for (int i = tid; i < 21 * VW; i += PREPTH) m = fmaxf(m, fabsf(Wm[h * 21 * VW + i]));
  for (int off = 32; off > 0; off >>= 1) m = fmaxf(m, __shfl_down(m, off));
  if ((tid & 63) == 0) red[tid >> 6] = m;
  __syncthreads();
  if (tid == 0) {
    m = fmaxf(fmaxf(red[0], red[1]), fmaxf(red[2], red[3]));
    m = fmaxf(m, 1e-20f);
    ((float*)(ws + OFF_SCF))[h]  = m / 16129.f;   // max/(127*127)
    ((float*)(ws + OFF_SINV))[h] = 127.f / m;
  }
}

// -------- prep 2: pack W1/W2 bf16 frags, Wm i8 frags, bm slices --------
__global__ void prep_pack(const float* __restrict__ Wvf1, const float* __restrict__ Wvf2,
                          const float* __restrict__ Wm, const float* __restrict__ bmv,
                          char* __restrict__ ws) {
  int idx = blockIdx.x * blockDim.x + threadIdx.x;
  if (idx < 98304) {
    u16* w16 = (u16*)(ws + OFF_FRAG16);
    float val;
    if (idx < 32768) {
      int e = idx;
      int j = e & 7, ln = (e >> 3) & 63, nt = (e >> 9) & 15, kk = e >> 13;
      val = Wvf1[(nt * 16 + (ln & 15)) * H + kk * 32 + (ln >> 4) * 8 + j];
    } else {
      int e = idx - 32768;
      int j = e & 7, ln = (e >> 3) & 63, nt = (e >> 9) & 15, kk = e >> 13;
      val = Wvf2[(nt * 16 + (ln & 15)) * VW + kk * 32 + (ln >> 4) * 8 + j];
    }
    w16[idx] = bf16u(val);
  } else if (idx < 98304 + 688128) {
    int b = idx - 98304;
    int j = b & 15, lane = (b >> 4) & 63, kk = (b >> 10) & 3, rem = b >> 12;
    int l = rem % 21, nt = rem / 21;
    int h = nt * 16 + (lane & 15);
    int w = kk * 64 + (lane >> 4) * 16 + j;
    float sinv = ((const float*)(ws + OFF_SINV))[h];
    float val = Wm[(size_t)(h * 21 + l) * VW + w];
    int q = (int)lrintf(val * sinv);
    q = min(127, max(-127, q));
    ((signed char*)(ws + OFF_WMQ))[b] = (signed char)q;
  } else if (idx < 98304 + 688128 + 2688) {
    int b = idx - (98304 + 688128);
    int hh = b & 15, rem = b >> 4;
    int l = rem % 21, nt = rem / 21;
    ((float*)(ws + OFF_BMF))[b] = bmv[(nt * 16 + hh) * 21 + l];
  }
}

// -------- main persistent kernel: 4-phase dual-tile pipeline --------
__global__ __launch_bounds__(NTH, 1) void rde_main(
    const float* __restrict__ logsig, const float* __restrict__ x0,
    const float* __restrict__ W1, const float* __restrict__ b1,
    const float* __restrict__ bvf1, const float* __restrict__ bvf2,
    const float* __restrict__ W2, const float* __restrict__ b2,
    char* __restrict__ ws, float* __restrict__ out) {
  __shared__ __align__(16) signed char WmL[86016];    // i8 Wm slice (shared)
  __shared__ __align__(16) u16   YB [2][BT][H + 8];   // per-tile bf16 y
  __shared__ __align__(16) u16   V1R[BT][VW + 8];     // time-shared between tiles
  __shared__ __align__(16) signed char V2QH[4096];    // time-shared
  __shared__ __align__(16) float LSF[2][2][21][BT];   // [tile][parity][l][r]
  __shared__ __align__(16) float part[8][BT][17];     // time-shared
  __shared__ __align__(16) float bmL[336];
  __shared__ float scL[16];
  __shared__ float LG[32][10];

  const int tid = threadIdx.x;
  const int lane = tid & 63;
  const int wv = tid >> 6;     // 0..7
  const int c = lane & 15;
  const int kg = lane >> 4;
  const int bid = blockIdx.x;
  const int Gp = (bid & 7) * 4 + (bid >> 6);  // 0..31; pair members share bid%8 (XCD heuristic)
  const int t = (bid >> 3) & 7;               // h-slice 0..7
  const int b0 = Gp * 32;
  unsigned* __restrict__ ybuf = (unsigned*)(ws + OFF_YBUF);
  const s16x8* __restrict__ fr16 = (const s16x8*)(ws + OFF_FRAG16);
  const f32x4 zf = {0.f, 0.f, 0.f, 0.f};
  const i32x4 zi = {0, 0, 0, 0};

  // persistent register weights: wave handles n-tiles {2wv, 2wv+1}
  s16x8 w1r[2][4], w2r[2][8];
#pragma unroll
  for (int n = 0; n < 2; ++n) {
#pragma unroll
    for (int kk = 0; kk < 4; ++kk) w1r[n][kk] = fr16[(kk * 16 + wv * 2 + n) * 64 + lane];
#pragma unroll
    for (int kk = 0; kk < 8; ++kk) w2r[n][kk] = fr16[4096 + (kk * 16 + wv * 2 + n) * 64 + lane];
  }
  float bv1[2], bv2[2];
#pragma unroll
  for (int n = 0; n < 2; ++n) {
    bv1[n] = bvf1[wv * 32 + n * 16 + c];
    bv2[n] = bvf2[wv * 32 + n * 16 + c];
  }

  {  // Wm slice -> LDS (once)
    const i32x4* wsrc = (const i32x4*)(ws + OFF_WMQ + t * 86016);
    i32x4* wdst = (i32x4*)WmL;
    for (int e = tid; e < 5376; e += NTH) wdst[e] = wsrc[e];
  }
  if (tid < 16) scL[tid] = ((const float*)(ws + OFF_SCF))[t * 16 + tid];
  for (int e = tid; e < 336; e += NTH) bmL[e] = ((const float*)(ws + OFF_BMF))[t * 336 + e];

  // y0 = x0 @ W1^T + b1 for both tiles (full YB + own state elements)
  for (int e = tid; e < 2 * BT * H; e += NTH) {
    int tt = e >> 11, r = (e >> 7) & 15, h = e & 127;
    float a = b1[h];
#pragma unroll
    for (int d = 0; d < 6; ++d) a += x0[(b0 + tt * 16 + r) * 6 + d] * W1[h * 6 + d];
    YB[tt][r][h] = bf16u(a);
  }
  float y0s = 0.f, y1s = 0.f, yp0s = 0.f, yp1s = 0.f;
  if (tid < 256) {
    int r = tid >> 4, hh = tid & 15, h = t * 16 + hh;
    float a0 = b1[h], a1 = b1[h];
#pragma unroll
    for (int d = 0; d < 6; ++d) {
      a0 += x0[(b0 + r) * 6 + d] * W1[h * 6 + d];
      a1 += x0[(b0 + 16 + r) * 6 + d] * W1[h * 6 + d];
    }
    y0s = a0; y1s = a1;
  }

  // ---- pipeline stage helpers ----
  auto STAGE = [&](int T, int iv) {
    for (int e = tid; e < BT * 21; e += NTH) {
      int r = e / 21, l = e - r * 21;
      LSF[T][iv & 1][l][r] = logsig[((size_t)(b0 + T * 16 + r) * NI + iv) * 22 + 1 + l];
    }
  };
  auto S1 = [&](int T) {  // YB[T] -> V1R (relu(y @ W1^T + b1))
    s16x8 ay0 = *(const s16x8*)&YB[T][c][0 * 32 + kg * 8];
    s16x8 ay1 = *(const s16x8*)&YB[T][c][1 * 32 + kg * 8];
    s16x8 ay2 = *(const s16x8*)&YB[T][c][2 * 32 + kg * 8];
    s16x8 ay3 = *(const s16x8*)&YB[T][c][3 * 32 + kg * 8];
    f32x4 pA = MFMA_BF16(ay0, w1r[0][0], zf), pB = MFMA_BF16(ay0, w1r[1][0], zf);
    pA = MFMA_BF16(ay1, w1r[0][1], pA);  pB = MFMA_BF16(ay1, w1r[1][1], pB);
    pA = MFMA_BF16(ay2, w1r[0][2], pA);  pB = MFMA_BF16(ay2, w1r[1][2], pB);
    pA = MFMA_BF16(ay3, w1r[0][3], pA);  pB = MFMA_BF16(ay3, w1r[1][3], pB);
#pragma unroll
    for (int q = 0; q < 4; ++q) {
      V1R[kg * 4 + q][wv * 32 + c]      = bf16u(fmaxf(pA[q] + bv1[0], 0.f));
      V1R[kg * 4 + q][wv * 32 + 16 + c] = bf16u(fmaxf(pB[q] + bv1[1], 0.f));
    }
  };
  auto S2 = [&]() {  // V1R -> V2QH (tanh + i8 quantize, hi only)
    s16x8 av0 = *(const s16x8*)&V1R[c][0 * 32 + kg * 8];
    s16x8 av1 = *(const s16x8*)&V1R[c][1 * 32 + kg * 8];
    s16x8 av2 = *(const s16x8*)&V1R[c][2 * 32 + kg * 8];
    s16x8 av3 = *(const s16x8*)&V1R[c][3 * 32 + kg * 8];
    s16x8 av4 = *(const s16x8*)&V1R[c][4 * 32 + kg * 8];
    s16x8 av5 = *(const s16x8*)&V1R[c][5 * 32 + kg * 8];
    s16x8 av6 = *(const s16x8*)&V1R[c][6 * 32 + kg * 8];
    s16x8 av7 = *(const s16x8*)&V1R[c][7 * 32 + kg * 8];
    f32x4 pA = MFMA_BF16(av0, w2r[0][0], zf), pB = MFMA_BF16(av0, w2r[1][0], zf);
    pA = MFMA_BF16(av1, w2r[0][1], pA);  pB = MFMA_BF16(av1, w2r[1][1], pB);
    pA = MFMA_BF16(av2, w2r[0][2], pA);  pB = MFMA_BF16(av2, w2r[1][2], pB);
    pA = MFMA_BF16(av3, w2r[0][3], pA);  pB = MFMA_BF16(av3, w2r[1][3], pB);
    pA = MFMA_BF16(av4, w2r[0][4], pA);  pB = MFMA_BF16(av4, w2r[1][4], pB);
    pA = MFMA_BF16(av5, w2r[0][5], pA);  pB = MFMA_BF16(av5, w2r[1][5], pB);
    pA = MFMA_BF16(av6, w2r[0][6], pA);  pB = MFMA_BF16(av6, w2r[1][6], pB);
    pA = MFMA_BF16(av7, w2r[0][7], pA);  pB = MFMA_BF16(av7, w2r[1][7], pB);
#pragma unroll
    for (int n = 0; n < 2; ++n) {
      f32x4 p = n ? pB : pA;
#pragma unroll
      for (int q = 0; q < 4; ++q) {
        float x = p[q] + bv2[n];
        float e2 = __expf(2.f * x);
        float t127 = fmaf(-254.f, __builtin_amdgcn_rcpf(e2 + 1.f), 127.f);  // 127*tanh
        int bo = ((wv >> 1) * 64 + ((wv & 1) * 2 + n) * 16 + kg * 4 + q) * 16 + c;
        V2QH[bo] = (signed char)(int)rintf(t127);
      }
    }
  };
  auto S3 = [&](int T, int lsb_) {  // V2QH x WmL -> part (ls-folded)
    i32x4 aih0 = *(const i32x4*)&V2QH[(0 * 64 + lane) * 16];
    i32x4 aih1 = *(const i32x4*)&V2QH[(1 * 64 + lane) * 16];
    i32x4 aih2 = *(const i32x4*)&V2QH[(2 * 64 + lane) * 16];
    i32x4 aih3 = *(const i32x4*)&V2QH[(3 * 64 + lane) * 16];
    const int nl = (wv < 5) ? 3 : 2;
    const int lb = (wv < 5) ? 3 * wv : 15 + 2 * (wv - 5);
    f32x4 acc = zf;
    for (int li = 0; li < nl; ++li) {
      int l = lb + li;
      const i32x4* bp = (const i32x4*)WmL + l * 256 + lane;
      i32x4 bq0 = bp[0], bq1 = bp[64], bq2 = bp[128], bq3 = bp[192];
      i32x4 PH = MFMA_I8(aih0, bq0, zi);
      PH = MFMA_I8(aih1, bq1, PH);
      PH = MFMA_I8(aih2, bq2, PH);
      PH = MFMA_I8(aih3, bq3, PH);
      f32x4 ls4 = *(const f32x4*)&LSF[T][lsb_][l][kg * 4];
#pragma unroll
      for (int q = 0; q < 4; ++q) acc[q] += ls4[q] * (float)PH[q];
    }
#pragma unroll
    for (int q = 0; q < 4; ++q) part[wv][kg * 4 + q][c] = acc[q];
  };
  auto S4 = [&](int T, int j, int lsb_, float& y, float& yp) {  // Heun + tagged store
    if (tid < 256) {
      int r = tid >> 4, hh = tid & 15;
      float s = ((part[0][r][hh] + part[1][r][hh]) + (part[2][r][hh] + part[3][r][hh])) +
                ((part[4][r][hh] + part[5][r][hh]) + (part[6][r][hh] + part[7][r][hh]));
      float bmd = 0.f;
#pragma unroll
      for (int l = 0; l < 21; ++l) bmd += LSF[T][lsb_][l][r] * bmL[l * 16 + hh];
      float raw = scL[hh] * s + bmd;
      float yn;
      if (!(j & 1)) { yp = y + 0.5f * raw; yn = y + raw; }
      else          { y = yp + 0.5f * raw; yn = y; }
      unsigned v = ((unsigned)(j + 1) << 16) | (unsigned)bf16u(yn);
      __hip_atomic_store(&ybuf[((Gp * 2 + T) * 2 + (j & 1)) * 2048 + r * 128 + t * 16 + hh],
                         v, __ATOMIC_RELAXED, __HIP_MEMORY_SCOPE_AGENT);
    }
  };
  auto S5 = [&](int T, int j) {  // poll peers' tags, rebuild YB[T]
    const unsigned tg = (unsigned)(j + 1);
    const unsigned* pb = ybuf + ((Gp * 2 + T) * 2 + (j & 1)) * 2048;
    unsigned v0, v1, v2, v3;
#pragma unroll 1
    for (int sp = 0; sp < 60000; ++sp) {
      v0 = __hip_atomic_load(&pb[tid],        __ATOMIC_RELAXED, __HIP_MEMORY_SCOPE_AGENT);
      v1 = __hip_atomic_load(&pb[tid + 512],  __ATOMIC_RELAXED, __HIP_MEMORY_SCOPE_AGENT);
      v2 = __hip_atomic_load(&pb[tid + 1024], __ATOMIC_RELAXED, __HIP_MEMORY_SCOPE_AGENT);
      v3 = __hip_atomic_load(&pb[tid + 1536], __ATOMIC_RELAXED, __HIP_MEMORY_SCOPE_AGENT);
      unsigned mn = min(min(v0 >> 16, v1 >> 16), min(v2 >> 16, v3 >> 16));
      if (mn == tg) break;
    }
    YB[T][tid >> 7][tid & 127] = (u16)(v0 & 0xffffu);
    YB[T][(tid + 512) >> 7][(tid + 512) & 127] = (u16)(v1 & 0xffffu);
    YB[T][(tid + 1024) >> 7][(tid + 1024) & 127] = (u16)(v2 & 0xffffu);
    YB[T][(tid + 1536) >> 7][(tid + 1536) & 127] = (u16)(v3 & 0xffffu);
  };

  __syncthreads();

  // ---- pipeline prologue: tile B runs S1,S2 of sub-step 0
  STAGE(1, 0);
  __syncthreads();
  S1(1);
  __syncthreads();
  S2();
  __syncthreads();

#pragma unroll 1
  for (int j = 0; j < 2 * NSTEPS; ++j) {
    const int step_ = j >> 1, sub_ = j & 1;
    const int lsb_ = (sub_ ? step_ : (step_ > 0 ? step_ - 1 : 0)) & 1;
    // p0: S1(A,j) || S3(B,j)
    if (!sub_) STAGE(0, step_);
    S1(0);
    S3(1, lsb_);
    __syncthreads();
    // p1: store B early, compute S2(A), poll B late
    S4(1, j, lsb_, y1s, yp1s);
    S2();
    S5(1, j);
    __syncthreads();
    // p2: S3(A,j) || S1(B,j+1)
    S3(0, lsb_);
    if (j < 2 * NSTEPS - 1) {
      if (sub_) STAGE(1, (j + 1) >> 1);
      S1(1);
    }
    __syncthreads();
    // p3: store A early, compute S2(B,j+1), poll A late
    S4(0, j, lsb_, y0s, yp0s);
    if (j < 2 * NSTEPS - 1) S2();
    S5(0, j);
    __syncthreads();
  }

  // ---- logits + softmax (slice-0 WG of each pair; 32 rows)
  if (t == 0) {
    for (int e = tid; e < 32 * 10; e += NTH) {
      int rr = e / 10, cc = e - rr * 10;
      float a = b2[cc];
#pragma unroll 4
      for (int h = 0; h < H; ++h) a += b2f(YB[rr >> 4][rr & 15][h]) * W2[cc * H + h];
      LG[rr][cc] = a;
    }
    __syncthreads();
    if (tid < 32) {
      float mx = -1e30f;
#pragma unroll
      for (int cc = 0; cc < 10; ++cc) mx = fmaxf(mx, LG[tid][cc]);
      float ex[10]; float s = 0.f;
#pragma unroll
      for (int cc = 0; cc < 10; ++cc) { ex[cc] = expf(LG[tid][cc] - mx); s += ex[cc]; }
      float inv = 1.f / s;
#pragma unroll
      for (int cc = 0; cc < 10; ++cc) out[(b0 + tid) * 10 + cc] = ex[cc] * inv;
    }
  }
}

extern "C" void kernel_launch(void* const* d_in, const int* in_sizes, int n_in,
                              void* d_out, int out_size, void* d_ws, size_t ws_size,
                              hipStream_t stream) {
  (void)in_sizes; (void)n_in; (void)out_size; (void)ws_size;
  const float* logsig = (const float*)d_in[1];
  const float* x0     = (const float*)d_in[2];
  const float* Wvf1   = (const float*)d_in[3];
  const float* bvf1   = (const float*)d_in[4];
  const float* Wvf2   = (const float*)d_in[5];
  const float* bvf2   = (const float*)d_in[6];
  const float* Wm     = (const float*)d_in[7];
  const float* bmv    = (const float*)d_in[8];
  const float* W1     = (const float*)d_in[9];
  const float* b1     = (const float*)d_in[10];
  const float* W2     = (const float*)d_in[11];
  const float* b2     = (const float*)d_in[12];
  char* ws = (char*)d_ws;

  prep_scales<<<128, PREPTH, 0, stream>>>(Wm, ws);
  prep_pack<<<3083, PREPTH, 0, stream>>>(Wvf1, Wvf2, Wm, bmv, ws);
  hipMemsetAsync(ws + OFF_YBUF, 0, YBUF_BYTES, stream);  // kill stale tags each call
  rde_main<<<NWG, NTH, 0, stream>>>(logsig, x0, W1, b1, bvf1, bvf2, W2, b2, ws,
                                    (float*)d_out);
}